// Round 1
// baseline (4914.809 us; speedup 1.0000x reference)
//
#include <hip/hip_runtime.h>
#include <hip/hip_fp16.h>

// Problem constants
#define BB   4
#define NN   8192
#define MM   2048
#define KNNK 16
#define DD   128
#define DPC  64
#define WCC  64
#define OCC  256
#define KTOT 4224          // DPC*WCC + DD
#define EPSV 1e-5f

#define NPTS_TOT (BB*NN)         // 32768 dense points
#define CNT1     (BB*NN*KNNK)    // 524288 point-neighbors

// stats region float indices
enum { REL0=0, SC1=16, SH1=80, SUM2=144, SQ2=208, SC2=272, SH2=336,
       SUM3=400, SQ3=464, SC3=528, SH3=592, SUMF=656, SQF=912, SCF=1168, SHF=1424 };

// workspace byte offsets
#define IDX_OFF 0u
#define ST_OFF  2097152u                 // B*N*K*4
#define WFT_OFF (ST_OFF + 8192u)
#define Y_OFF   (WFT_OFF + 2162688u)     // OCC*KTOT*2

typedef _Float16 half2_t __attribute__((ext_vector_type(2)));

#if __has_builtin(__builtin_amdgcn_fdot2)
__device__ __forceinline__ float fdot2f(half2_t a, half2_t b, float c) {
  return __builtin_amdgcn_fdot2(a, b, c, false);
}
#else
__device__ __forceinline__ float fdot2f(half2_t a, half2_t b, float c) {
  return c + (float)a[0]*(float)b[0] + (float)a[1]*(float)b[1];
}
#endif

// ---------------------------------------------------------------------------
// KNN: per dense point, top-16 smallest d2 among 2048 sparse points.
// Also accumulates first/second moments of rel (for closed-form BN1 stats).
__global__ __launch_bounds__(256) void knn_kernel(
    const float* __restrict__ xyz, const float* __restrict__ nxyz,
    int* __restrict__ idxo, float* __restrict__ stats) {
  __shared__ float sx[MM], sy[MM], sz[MM], sn[MM];
  __shared__ float sred[9];
  int b = blockIdx.y;
  const float* np_ = nxyz + (size_t)b*MM*3;
  for (int i = threadIdx.x; i < MM; i += 256) {
    float x = np_[i*3+0], y = np_[i*3+1], z = np_[i*3+2];
    sx[i]=x; sy[i]=y; sz[i]=z; sn[i]=x*x+y*y+z*z;
  }
  if (threadIdx.x < 9) sred[threadIdx.x] = 0.f;
  __syncthreads();
  int n = blockIdx.x*256 + threadIdx.x;
  const float* pp = xyz + ((size_t)b*NN + n)*3;
  float px=pp[0], py=pp[1], pz=pp[2];
  float pn = px*px + py*py + pz*pz;
  float dist[KNNK]; int ind[KNNK];
  #pragma unroll
  for (int k=0;k<KNNK;k++){ dist[k]=3.0e38f; ind[k]=0; }
  for (int m=0;m<MM;m++) {
    float d = pn + sn[m] - 2.0f*(px*sx[m] + py*sy[m] + pz*sz[m]);
    if (d < dist[KNNK-1]) {          // strict <: equal keeps earlier index (matches top_k)
      float cd = d; int ci = m;
      #pragma unroll
      for (int j=0;j<KNNK;j++) {
        if (cd < dist[j]) { float td=dist[j]; int ti=ind[j];
                            dist[j]=cd; ind[j]=ci; cd=td; ci=ti; }
      }
    }
  }
  int* op = idxo + ((size_t)b*NN + n)*KNNK;
  float s0=0,s1=0,s2=0,s3=0,s4=0,s5=0,s6=0,s7=0,s8=0;
  #pragma unroll
  for (int k=0;k<KNNK;k++) {
    op[k] = ind[k];
    float rx = sx[ind[k]]-px, ry = sy[ind[k]]-py, rz = sz[ind[k]]-pz;
    s0+=rx; s1+=ry; s2+=rz;
    s3+=rx*rx; s4+=rx*ry; s5+=rx*rz; s6+=ry*ry; s7+=ry*rz; s8+=rz*rz;
  }
  atomicAdd(&sred[0],s0); atomicAdd(&sred[1],s1); atomicAdd(&sred[2],s2);
  atomicAdd(&sred[3],s3); atomicAdd(&sred[4],s4); atomicAdd(&sred[5],s5);
  atomicAdd(&sred[6],s6); atomicAdd(&sred[7],s7); atomicAdd(&sred[8],s8);
  __syncthreads();
  if (threadIdx.x < 9) atomicAdd(&stats[REL0 + threadIdx.x], sred[threadIdx.x]);
}

// ---------------------------------------------------------------------------
// BN1 scale/shift from rel moments: s1 = rel @ w1 is linear in rel.
__global__ void bn1_kernel(const float* __restrict__ w1, const float* __restrict__ g1,
                           const float* __restrict__ b1, float* __restrict__ stats) {
  int d = threadIdx.x;
  float inv = 1.0f / (float)CNT1;
  float mx=stats[0]*inv, my=stats[1]*inv, mz=stats[2]*inv;
  float xx=stats[3]*inv, xy=stats[4]*inv, xz=stats[5]*inv,
        yy=stats[6]*inv, yz=stats[7]*inv, zz=stats[8]*inv;
  float wx=w1[0*WCC+d], wy=w1[1*WCC+d], wz=w1[2*WCC+d];
  float m  = mx*wx + my*wy + mz*wz;
  float e2 = wx*wx*xx + wy*wy*yy + wz*wz*zz + 2.0f*(wx*wy*xy + wx*wz*xz + wy*wz*yz);
  float v  = e2 - m*m;
  float sc = rsqrtf(v + EPSV) * g1[d];
  stats[SC1+d] = sc;
  stats[SH1+d] = b1[d] - m*sc;
}

// generic BN prep from per-channel sum/sumsq
__global__ void bnsmall_kernel(const float* __restrict__ g, const float* __restrict__ b,
                               float* __restrict__ stats, int sumOff, int sqOff,
                               int scOff, int shOff, float inv) {
  int d = threadIdx.x;
  float m = stats[sumOff+d]*inv;
  float v = stats[sqOff+d]*inv - m*m;
  float sc = rsqrtf(v + EPSV) * g[d];
  stats[scOff+d] = sc;
  stats[shOff+d] = b[d] - m*sc;
}

// ---------------------------------------------------------------------------
// Stats pass for BN2 (LAYERS=2) / BN3 (LAYERS=3). One wave per dense point
// batch of 16 neighbors; lane = channel.
template<int LAYERS>
__global__ __launch_bounds__(256) void stats_kernel(
    const float* __restrict__ xyz, const float* __restrict__ nxyz,
    const int* __restrict__ idx, const float* __restrict__ w1,
    const float* __restrict__ w2, const float* __restrict__ w3,
    float* __restrict__ stats) {
  __shared__ __align__(16) float w2s[WCC*WCC];
  __shared__ __align__(16) float w3s[WCC*WCC];
  __shared__ __align__(16) float hbuf[4][KNNK][WCC];
  __shared__ float red[4][128];
  int tid = threadIdx.x, lane = tid & 63, wid = tid >> 6;
  for (int i = tid; i < WCC*WCC; i += 256) { w2s[i] = w2[i]; if (LAYERS==3) w3s[i] = w3[i]; }
  __syncthreads();
  float w1x = w1[lane], w1y = w1[64+lane], w1z = w1[128+lane];
  float sc1 = stats[SC1+lane], sh1 = stats[SH1+lane];
  float sc2 = stats[SC2+lane], sh2 = stats[SH2+lane];  // zeros when LAYERS==2 (unused)
  float* hb = &hbuf[wid][0][0];
  float sum = 0.f, sq = 0.f;
  int pstart = (blockIdx.x*4 + wid) * 4;     // 4 points per wave
  for (int pi = 0; pi < 4; ++pi) {
    int p = pstart + pi;
    int b = p >> 13;
    const float* pp = xyz + (size_t)p*3;
    float px=pp[0], py=pp[1], pz=pp[2];
    const int* ip = idx + (size_t)p*KNNK;
    #pragma unroll
    for (int k=0;k<KNNK;k++) {
      int j = ip[k];
      const float* q = nxyz + ((size_t)b*MM + j)*3;
      float rx=q[0]-px, ry=q[1]-py, rz=q[2]-pz;
      float s1v = rx*w1x + ry*w1y + rz*w1z;
      hb[k*WCC + lane] = fmaxf(s1v*sc1 + sh1, 0.f);
    }
    float s2[KNNK];
    #pragma unroll
    for (int k=0;k<KNNK;k++) s2[k]=0.f;
    #pragma unroll 2
    for (int c=0;c<WCC;c+=4) {
      float wa=w2s[(c+0)*WCC+lane], wb=w2s[(c+1)*WCC+lane],
            wc=w2s[(c+2)*WCC+lane], wd=w2s[(c+3)*WCC+lane];
      #pragma unroll
      for (int k=0;k<KNNK;k++) {
        float4 h = *(const float4*)(hb + k*WCC + c);
        s2[k] = fmaf(h.x,wa,fmaf(h.y,wb,fmaf(h.z,wc,fmaf(h.w,wd,s2[k]))));
      }
    }
    if (LAYERS==2) {
      #pragma unroll
      for (int k=0;k<KNNK;k++){ float v=s2[k]; sum+=v; sq+=v*v; }
    } else {
      #pragma unroll
      for (int k=0;k<KNNK;k++) hb[k*WCC+lane] = fmaxf(s2[k]*sc2 + sh2, 0.f);
      float s3[KNNK];
      #pragma unroll
      for (int k=0;k<KNNK;k++) s3[k]=0.f;
      #pragma unroll 2
      for (int c=0;c<WCC;c+=4) {
        float wa=w3s[(c+0)*WCC+lane], wb=w3s[(c+1)*WCC+lane],
              wc=w3s[(c+2)*WCC+lane], wd=w3s[(c+3)*WCC+lane];
        #pragma unroll
        for (int k=0;k<KNNK;k++) {
          float4 h = *(const float4*)(hb + k*WCC + c);
          s3[k] = fmaf(h.x,wa,fmaf(h.y,wb,fmaf(h.z,wc,fmaf(h.w,wd,s3[k]))));
        }
      }
      #pragma unroll
      for (int k=0;k<KNNK;k++){ float v=s3[k]; sum+=v; sq+=v*v; }
    }
  }
  red[wid][lane] = sum; red[wid][64+lane] = sq;
  __syncthreads();
  if (tid < 128) {
    float v = red[0][tid]+red[1][tid]+red[2][tid]+red[3][tid];
    atomicAdd(&stats[(LAYERS==2 ? SUM2 : SUM3) + tid], v);
  }
}

// ---------------------------------------------------------------------------
// wf (KTOT x OCC f32) -> wfT (OCC x KTOT f16), tiled transpose
__global__ __launch_bounds__(256) void wft_kernel(const float* __restrict__ wf,
                                                  __half* __restrict__ wfT) {
  __shared__ __half t[64][65];
  int k0 = blockIdx.x*64, o0 = blockIdx.y*64;
  int tid = threadIdx.x, c = tid & 63, r4 = tid >> 6;
  #pragma unroll
  for (int i=0;i<16;i++) {
    int kr = i*4 + r4;
    t[kr][c] = __float2half(wf[(size_t)(k0+kr)*OCC + o0 + c]);
  }
  __syncthreads();
  #pragma unroll
  for (int i=0;i<16;i++) {
    int orow = i*4 + r4;
    wfT[(size_t)(o0+orow)*KTOT + k0 + c] = t[c][orow];
  }
}

// ---------------------------------------------------------------------------
// Main fused kernel: 8 dense points per block.
// Phase 1: recompute weightnet chain (wave per 2 points, lane = channel) -> Wm regs
// Phase 2: agg = G^T Wm, written to LDS as f16 X-tile [8][4096]
// Phase 3: y[8][256] = X @ wfT(f16) via v_dot2_f32_f16 + feature tail
__global__ __launch_bounds__(256) void fused_kernel(
    const float* __restrict__ xyz, const float* __restrict__ nxyz,
    const float* __restrict__ nfeat, const float* __restrict__ feat,
    const int* __restrict__ idx, const float* __restrict__ w1,
    const float* __restrict__ w2, const float* __restrict__ w3,
    const float* __restrict__ stats, const __half* __restrict__ wfT,
    float* __restrict__ y) {
  __shared__ __align__(16) char smem_raw[65536];
  float* w2s = (float*)smem_raw;                 // [4096]
  float* w3s = w2s + 4096;                       // [4096]
  float* hball = w3s + 4096;                     // [4][16][64]
  __half* Xs = (__half*)smem_raw;                // [8][4096] (phase 2+)

  int tid = threadIdx.x, lane = tid & 63, wid = tid >> 6;
  for (int i=tid;i<WCC*WCC;i+=256){ w2s[i]=w2[i]; w3s[i]=w3[i]; }
  __syncthreads();

  float w1x=w1[lane], w1y=w1[64+lane], w1z=w1[128+lane];
  float sc1=stats[SC1+lane], sh1=stats[SH1+lane];
  float sc2=stats[SC2+lane], sh2=stats[SH2+lane];
  float sc3=stats[SC3+lane], sh3=stats[SH3+lane];
  float* hb = hball + wid*KNNK*WCC;

  float wm[2][KNNK];
  int   jn[2][KNNK];
  int p0 = blockIdx.x*8 + wid*2;

  #pragma unroll
  for (int pt=0; pt<2; ++pt) {
    int p = p0 + pt;
    int b = p >> 13;
    const float* pp = xyz + (size_t)p*3;
    float px=pp[0], py=pp[1], pz=pp[2];
    const int* ip = idx + (size_t)p*KNNK;
    #pragma unroll
    for (int k=0;k<KNNK;k++) {
      int j = ip[k]; jn[pt][k] = j;
      const float* q = nxyz + ((size_t)b*MM + j)*3;
      float rx=q[0]-px, ry=q[1]-py, rz=q[2]-pz;
      float s1v = rx*w1x + ry*w1y + rz*w1z;
      hb[k*WCC + lane] = fmaxf(s1v*sc1 + sh1, 0.f);
    }
    float s2[KNNK];
    #pragma unroll
    for (int k=0;k<KNNK;k++) s2[k]=0.f;
    #pragma unroll 2
    for (int c=0;c<WCC;c+=4) {
      float wa=w2s[(c+0)*WCC+lane], wb=w2s[(c+1)*WCC+lane],
            wc=w2s[(c+2)*WCC+lane], wd=w2s[(c+3)*WCC+lane];
      #pragma unroll
      for (int k=0;k<KNNK;k++) {
        float4 h = *(const float4*)(hb + k*WCC + c);
        s2[k] = fmaf(h.x,wa,fmaf(h.y,wb,fmaf(h.z,wc,fmaf(h.w,wd,s2[k]))));
      }
    }
    #pragma unroll
    for (int k=0;k<KNNK;k++) hb[k*WCC+lane] = fmaxf(s2[k]*sc2 + sh2, 0.f);
    float s3[KNNK];
    #pragma unroll
    for (int k=0;k<KNNK;k++) s3[k]=0.f;
    #pragma unroll 2
    for (int c=0;c<WCC;c+=4) {
      float wa=w3s[(c+0)*WCC+lane], wb=w3s[(c+1)*WCC+lane],
            wc=w3s[(c+2)*WCC+lane], wd=w3s[(c+3)*WCC+lane];
      #pragma unroll
      for (int k=0;k<KNNK;k++) {
        float4 h = *(const float4*)(hb + k*WCC + c);
        s3[k] = fmaf(h.x,wa,fmaf(h.y,wb,fmaf(h.z,wc,fmaf(h.w,wd,s3[k]))));
      }
    }
    #pragma unroll
    for (int k=0;k<KNNK;k++) wm[pt][k] = fmaxf(s3[k]*sc3 + sh3, 0.f);
  }
  __syncthreads();   // phase 1 done everywhere; LDS becomes X tile

  // Phase 2: agg rows -> Xs (lane = w channel)
  #pragma unroll
  for (int pt=0; pt<2; ++pt) {
    int p = p0 + pt;
    int b = p >> 13;
    int row = wid*2 + pt;
    const float* nfb = nfeat + (size_t)b*DPC*MM;
    #pragma unroll 2
    for (int d=0; d<DPC; ++d) {
      float a = 0.f;
      #pragma unroll
      for (int k=0;k<KNNK;k++) a = fmaf(nfb[d*MM + jn[pt][k]], wm[pt][k], a);
      Xs[row*4096 + d*64 + lane] = __float2half(a);
    }
  }
  __syncthreads();

  // Phase 3: GEMM. thread -> cols (o, o+128), rows rbase..rbase+3
  int o = tid & 127;
  int rbase = (tid >> 7) * 4;
  const __half* wr0 = wfT + (size_t)o * KTOT;
  const __half* wr1 = wfT + (size_t)(o+128) * KTOT;
  float acc0[4] = {0,0,0,0};
  float acc1[4] = {0,0,0,0};
  #pragma unroll 2
  for (int kk=0; kk<DPC*WCC; kk+=8) {
    uint4 wv0 = *(const uint4*)(wr0 + kk);
    uint4 wv1 = *(const uint4*)(wr1 + kk);
    half2_t b00=__builtin_bit_cast(half2_t, wv0.x), b01=__builtin_bit_cast(half2_t, wv0.y),
            b02=__builtin_bit_cast(half2_t, wv0.z), b03=__builtin_bit_cast(half2_t, wv0.w);
    half2_t b10=__builtin_bit_cast(half2_t, wv1.x), b11=__builtin_bit_cast(half2_t, wv1.y),
            b12=__builtin_bit_cast(half2_t, wv1.z), b13=__builtin_bit_cast(half2_t, wv1.w);
    #pragma unroll
    for (int r=0;r<4;r++) {
      uint4 xv = *(const uint4*)(Xs + (rbase+r)*4096 + kk);
      half2_t x0=__builtin_bit_cast(half2_t, xv.x), x1=__builtin_bit_cast(half2_t, xv.y),
              x2=__builtin_bit_cast(half2_t, xv.z), x3=__builtin_bit_cast(half2_t, xv.w);
      acc0[r]=fdot2f(x0,b00,acc0[r]); acc0[r]=fdot2f(x1,b01,acc0[r]);
      acc0[r]=fdot2f(x2,b02,acc0[r]); acc0[r]=fdot2f(x3,b03,acc0[r]);
      acc1[r]=fdot2f(x0,b10,acc1[r]); acc1[r]=fdot2f(x1,b11,acc1[r]);
      acc1[r]=fdot2f(x2,b12,acc1[r]); acc1[r]=fdot2f(x3,b13,acc1[r]);
    }
  }
  // feature tail (K = 4096..4223)
  #pragma unroll 2
  for (int c=0;c<DD;c++) {
    float f0 = __half2float(wr0[DPC*WCC + c]);
    float f1 = __half2float(wr1[DPC*WCC + c]);
    #pragma unroll
    for (int r=0;r<4;r++) {
      int p = blockIdx.x*8 + rbase + r;
      float fv = feat[((size_t)(p>>13)*DD + c)*NN + (p & 8191)];
      acc0[r] = fmaf(fv, f0, acc0[r]);
      acc1[r] = fmaf(fv, f1, acc1[r]);
    }
  }
  #pragma unroll
  for (int r=0;r<4;r++) {
    size_t p = (size_t)blockIdx.x*8 + rbase + r;
    y[p*OCC + o]       = acc0[r];
    y[p*OCC + o + 128] = acc1[r];
  }
}

// ---------------------------------------------------------------------------
__global__ __launch_bounds__(256) void statsf_kernel(const float* __restrict__ y,
                                                     float* __restrict__ stats) {
  int o = threadIdx.x;
  size_t r0 = (size_t)blockIdx.x * 128;
  float sum=0.f, sq=0.f;
  for (int r=0;r<128;r++) {
    float v = y[(r0+r)*OCC + o];
    sum += v; sq += v*v;
  }
  atomicAdd(&stats[SUMF+o], sum);
  atomicAdd(&stats[SQF+o], sq);
}

// transpose y (B*N, OC) -> out (B, OC, N) with BN+ReLU
__global__ __launch_bounds__(256) void final_kernel(const float* __restrict__ y,
    const float* __restrict__ stats, float* __restrict__ out) {
  __shared__ float t[64][65];
  int o0 = blockIdx.x*64, n0 = blockIdx.y*64, b = blockIdx.z;
  int tid = threadIdx.x, c = tid & 63, r4 = tid >> 6;
  #pragma unroll
  for (int i=0;i<16;i++) {
    int r = i*4 + r4;
    t[r][c] = y[((size_t)b*NN + n0 + r)*OCC + o0 + c];
  }
  __syncthreads();
  #pragma unroll
  for (int i=0;i<16;i++) {
    int orow = i*4 + r4;
    float sc = stats[SCF + o0 + orow], sh = stats[SHF + o0 + orow];
    float v = t[c][orow]*sc + sh;
    out[((size_t)b*OCC + o0 + orow)*NN + n0 + c] = fmaxf(v, 0.f);
  }
}

// ---------------------------------------------------------------------------
extern "C" void kernel_launch(void* const* d_in, const int* in_sizes, int n_in,
                              void* d_out, int out_size, void* d_ws, size_t ws_size,
                              hipStream_t stream) {
  const float* xyz   = (const float*)d_in[0];
  const float* nxyz  = (const float*)d_in[1];
  const float* feat  = (const float*)d_in[2];
  const float* nfeat = (const float*)d_in[3];
  const float* w1    = (const float*)d_in[4];
  const float* w2    = (const float*)d_in[5];
  const float* w3    = (const float*)d_in[6];
  const float* g1    = (const float*)d_in[7];
  const float* b1    = (const float*)d_in[8];
  const float* g2    = (const float*)d_in[9];
  const float* b2    = (const float*)d_in[10];
  const float* g3    = (const float*)d_in[11];
  const float* b3    = (const float*)d_in[12];
  const float* wf    = (const float*)d_in[13];
  const float* gf    = (const float*)d_in[14];
  const float* bf    = (const float*)d_in[15];

  char* ws = (char*)d_ws;
  int*    idx   = (int*)(ws + IDX_OFF);
  float*  stats = (float*)(ws + ST_OFF);
  __half* wfT   = (__half*)(ws + WFT_OFF);
  float*  yb    = (float*)(ws + Y_OFF);
  float*  outp  = (float*)d_out;

  hipMemsetAsync(stats, 0, 8192, stream);

  knn_kernel<<<dim3(NN/256, BB), 256, 0, stream>>>(xyz, nxyz, idx, stats);
  bn1_kernel<<<1, 64, 0, stream>>>(w1, g1, b1, stats);
  stats_kernel<2><<<2048, 256, 0, stream>>>(xyz, nxyz, idx, w1, w2, w3, stats);
  bnsmall_kernel<<<1, 64, 0, stream>>>(g2, b2, stats, SUM2, SQ2, SC2, SH2, 1.0f/(float)CNT1);
  stats_kernel<3><<<2048, 256, 0, stream>>>(xyz, nxyz, idx, w1, w2, w3, stats);
  bnsmall_kernel<<<1, 64, 0, stream>>>(g3, b3, stats, SUM3, SQ3, SC3, SH3, 1.0f/(float)CNT1);
  wft_kernel<<<dim3(KTOT/64, OCC/64), 256, 0, stream>>>(wf, wfT);
  fused_kernel<<<NPTS_TOT/8, 256, 0, stream>>>(xyz, nxyz, nfeat, feat, idx,
                                               w1, w2, w3, stats, wfT, yb);
  statsf_kernel<<<NPTS_TOT/128, 256, 0, stream>>>(yb, stats);
  bnsmall_kernel<<<1, 256, 0, stream>>>(gf, bf, stats, SUMF, SQF, SCF, SHF, 1.0f/(float)NPTS_TOT);
  final_kernel<<<dim3(OCC/64, NN/64, BB), 256, 0, stream>>>(yb, stats, outp);
}

// Round 3
// 1812.046 us; speedup vs baseline: 2.7123x; 2.7123x over previous
//
#include <hip/hip_runtime.h>

// Problem constants
#define BB   4
#define NN   8192
#define MM   2048
#define KNNK 16
#define DD   128
#define DPC  64
#define WCC  64
#define OCC  256
#define KTOT 4224          // DPC*WCC + DD
#define EPSV 1e-5f
#define NPTS (BB*NN)       // 32768
#define CNT1 (NPTS*KNNK)   // 524288

// stats region float indices
enum { REL0=0, SC1=16, SH1=80, SUM2=144, SQ2=208, SC2=272, SH2=336,
       SUM3=400, SQ3=464, SC3=528, SH3=592, SUMF=656, SQF=912, SCF=1168, SHF=1424 };

// workspace byte offsets
#define IDX_OFF   0u           // 32768*16*4 = 2 MB
#define ST_OFF    2097152u     // 8 KB
#define WFB_OFF   2105344u     // 132*16*64*8*2 = 2162688
#define NFT_OFF   4268032u     // 4*2048*64*4 = 2 MB
#define FTT_OFF   6365184u     // 32768*128*2 = 8388608
#define Y16_OFF   14753792u    // 32768*256*2 = 16777216
#define S23_OFF   31531008u    // 524288*64*2 = 67108864  (total ~94 MB)
#define CAND_OFF  S23_OFF      // cand (8.4 MB) aliases s23: dead before k2 runs

typedef _Float16 half8 __attribute__((ext_vector_type(8)));
typedef _Float16 half2t __attribute__((ext_vector_type(2)));
typedef float    f32x4 __attribute__((ext_vector_type(4)));

// ---------------------------------------------------------------------------
// KNN over one half (1024 candidates) of the sparse set.
__global__ __launch_bounds__(256) void knn_part(
    const float* __restrict__ xyz, const float* __restrict__ nxyz,
    float2* __restrict__ cand) {
  __shared__ float sx[1024], sy[1024], sz[1024], sn[1024];
  int b = blockIdx.z, h = blockIdx.y;
  int mbase = h * 1024;
  const float* np_ = nxyz + ((size_t)b*MM + mbase)*3;
  for (int i = threadIdx.x; i < 1024; i += 256) {
    float x = np_[i*3+0], y = np_[i*3+1], z = np_[i*3+2];
    sx[i]=x; sy[i]=y; sz[i]=z; sn[i]=x*x+y*y+z*z;
  }
  __syncthreads();
  int n = blockIdx.x*256 + threadIdx.x;
  const float* pp = xyz + ((size_t)b*NN + n)*3;
  float px=pp[0], py=pp[1], pz=pp[2];
  float pn = px*px + py*py + pz*pz;
  float dist[KNNK]; int ind[KNNK];
  #pragma unroll
  for (int k=0;k<KNNK;k++){ dist[k]=3.0e38f; ind[k]=0; }
  for (int m=0;m<1024;m++) {
    float d = pn + sn[m] - 2.0f*(px*sx[m] + py*sy[m] + pz*sz[m]);
    if (d < dist[KNNK-1]) {          // strict <: equal keeps earlier index
      float cd = d; int ci = mbase + m;
      #pragma unroll
      for (int j=0;j<KNNK;j++)
        if (cd < dist[j]) { float td=dist[j]; int ti=ind[j];
                            dist[j]=cd; ind[j]=ci; cd=td; ci=ti; }
    }
  }
  float2* op = cand + ((size_t)b*NN + n)*32 + h*16;
  #pragma unroll
  for (int k=0;k<KNNK;k++) op[k] = make_float2(dist[k], __int_as_float(ind[k]));
}

// Merge two sorted 16-lists -> final idx; accumulate rel first/second moments.
__global__ __launch_bounds__(256) void knn_merge(
    const float* __restrict__ xyz, const float* __restrict__ nxyz,
    const float2* __restrict__ cand, int* __restrict__ idxo,
    float* __restrict__ stats) {
  __shared__ float sred[9];
  if (threadIdx.x < 9) sred[threadIdx.x] = 0.f;
  __syncthreads();
  int p = blockIdx.x*256 + threadIdx.x;
  int b = p >> 13;
  const float2* ca = cand + (size_t)p*32;
  float dist[16]; int ind[16];
  #pragma unroll
  for (int k=0;k<16;k++) { float2 f = ca[k]; dist[k]=f.x; ind[k]=__float_as_int(f.y); }
  // insert half B (higher indices): strict < keeps A on ties (lower m wins)
  #pragma unroll
  for (int k=0;k<16;k++) {
    float2 f = ca[16+k];
    float cd = f.x; int ci = __float_as_int(f.y);
    if (cd < dist[15]) {
      #pragma unroll
      for (int j=0;j<16;j++)
        if (cd < dist[j]) { float td=dist[j]; int ti=ind[j];
                            dist[j]=cd; ind[j]=ci; cd=td; ci=ti; }
    }
  }
  const float* pp = xyz + (size_t)p*3;
  float px=pp[0], py=pp[1], pz=pp[2];
  int* op = idxo + (size_t)p*16;
  float s0=0,s1=0,s2=0,s3=0,s4=0,s5=0,s6=0,s7=0,s8=0;
  #pragma unroll
  for (int k=0;k<16;k++) {
    op[k] = ind[k];
    const float* q = nxyz + ((size_t)b*MM + ind[k])*3;
    float rx=q[0]-px, ry=q[1]-py, rz=q[2]-pz;
    s0+=rx; s1+=ry; s2+=rz;
    s3+=rx*rx; s4+=rx*ry; s5+=rx*rz; s6+=ry*ry; s7+=ry*rz; s8+=rz*rz;
  }
  atomicAdd(&sred[0],s0); atomicAdd(&sred[1],s1); atomicAdd(&sred[2],s2);
  atomicAdd(&sred[3],s3); atomicAdd(&sred[4],s4); atomicAdd(&sred[5],s5);
  atomicAdd(&sred[6],s6); atomicAdd(&sred[7],s7); atomicAdd(&sred[8],s8);
  __syncthreads();
  if (threadIdx.x < 9) atomicAdd(&stats[REL0 + threadIdx.x], sred[threadIdx.x]);
}

// ---------------------------------------------------------------------------
// BN1 closed form (s1 linear in rel).
__global__ void bn1_kernel(const float* __restrict__ w1, const float* __restrict__ g1,
                           const float* __restrict__ b1, float* __restrict__ stats) {
  int d = threadIdx.x;
  float inv = 1.0f / (float)CNT1;
  float mx=stats[0]*inv, my=stats[1]*inv, mz=stats[2]*inv;
  float xx=stats[3]*inv, xy=stats[4]*inv, xz=stats[5]*inv,
        yy=stats[6]*inv, yz=stats[7]*inv, zz=stats[8]*inv;
  float wx=w1[0*WCC+d], wy=w1[1*WCC+d], wz=w1[2*WCC+d];
  float m  = mx*wx + my*wy + mz*wz;
  float e2 = wx*wx*xx + wy*wy*yy + wz*wz*zz + 2.0f*(wx*wy*xy + wx*wz*xz + wy*wz*yz);
  float v  = e2 - m*m;
  float sc = rsqrtf(v + EPSV) * g1[d];
  stats[SC1+d] = sc;
  stats[SH1+d] = b1[d] - m*sc;
}

__global__ void bnsmall_kernel(const float* __restrict__ g, const float* __restrict__ b,
                               float* __restrict__ stats, int sumOff, int sqOff,
                               int scOff, int shOff, float inv) {
  int d = threadIdx.x;
  float m = stats[sumOff+d]*inv;
  float v = stats[sqOff+d]*inv - m*m;
  float sc = rsqrtf(v + EPSV) * g[d];
  stats[scOff+d] = sc;
  stats[shOff+d] = b[d] - m*sc;
}

// ---------------------------------------------------------------------------
// K2: rel -> h1 -> s2; BN2 stats; store s2 (f16). 32 pts/block, 8/wave, lane=w.
__global__ __launch_bounds__(256, 4) void k2_kernel(
    const float* __restrict__ xyz, const float* __restrict__ nxyz,
    const int* __restrict__ idx, const float* __restrict__ w1,
    const float* __restrict__ w2, const float* __restrict__ stats,
    _Float16* __restrict__ s23, float* __restrict__ statw) {
  __shared__ __align__(16) float hb[4][KNNK*WCC];
  __shared__ float red[4][128];
  int tid=threadIdx.x, lane=tid&63, wid=tid>>6;
  float w2col[64];
  #pragma unroll
  for (int c=0;c<64;c++) w2col[c] = w2[c*64+lane];
  float w1x=w1[lane], w1y=w1[64+lane], w1z=w1[128+lane];
  float sc1=stats[SC1+lane], sh1=stats[SH1+lane];
  float* hbw = hb[wid];
  float sum=0.f, sq=0.f;
  int pbase = blockIdx.x*32 + wid*8;
  for (int pt=0; pt<8; ++pt) {
    int p = pbase + pt;
    int b = p >> 13;
    const float* pp = xyz + (size_t)p*3;
    float px=pp[0], py=pp[1], pz=pp[2];
    const int* ip = idx + (size_t)p*16;
    #pragma unroll
    for (int k=0;k<16;k++) {
      int j = ip[k];
      const float* q = nxyz + ((size_t)b*MM + j)*3;
      float s1v = (q[0]-px)*w1x + (q[1]-py)*w1y + (q[2]-pz)*w1z;
      hbw[k*64+lane] = fmaxf(s1v*sc1 + sh1, 0.f);
    }
    for (int k=0;k<16;k++) {
      float acc = 0.f;
      #pragma unroll
      for (int c=0;c<64;c+=4) {
        float4 h = *(const float4*)&hbw[k*64+c];
        acc = fmaf(h.x, w2col[c+0], acc);
        acc = fmaf(h.y, w2col[c+1], acc);
        acc = fmaf(h.z, w2col[c+2], acc);
        acc = fmaf(h.w, w2col[c+3], acc);
      }
      sum += acc; sq += acc*acc;
      s23[((size_t)p*16 + k)*64 + lane] = (_Float16)acc;
    }
  }
  red[wid][lane]=sum; red[wid][64+lane]=sq;
  __syncthreads();
  if (tid < 128) {
    float v = red[0][tid]+red[1][tid]+red[2][tid]+red[3][tid];
    atomicAdd(&statw[SUM2+tid], v);   // SQ2 = SUM2+64, contiguous
  }
}

// K3: s2 -> h2 -> s3 (in place); BN3 stats.
__global__ __launch_bounds__(256, 4) void k3_kernel(
    const float* __restrict__ w3, const float* __restrict__ stats,
    _Float16* __restrict__ s23, float* __restrict__ statw) {
  __shared__ __align__(16) float hb[4][KNNK*WCC];
  __shared__ float red[4][128];
  int tid=threadIdx.x, lane=tid&63, wid=tid>>6;
  float w3col[64];
  #pragma unroll
  for (int c=0;c<64;c++) w3col[c] = w3[c*64+lane];
  float sc2=stats[SC2+lane], sh2=stats[SH2+lane];
  float* hbw = hb[wid];
  float sum=0.f, sq=0.f;
  int pbase = blockIdx.x*32 + wid*8;
  for (int pt=0; pt<8; ++pt) {
    size_t p = pbase + pt;
    #pragma unroll
    for (int k=0;k<16;k++) {
      float v = (float)s23[(p*16 + k)*64 + lane];
      hbw[k*64+lane] = fmaxf(v*sc2 + sh2, 0.f);
    }
    for (int k=0;k<16;k++) {
      float acc = 0.f;
      #pragma unroll
      for (int c=0;c<64;c+=4) {
        float4 h = *(const float4*)&hbw[k*64+c];
        acc = fmaf(h.x, w3col[c+0], acc);
        acc = fmaf(h.y, w3col[c+1], acc);
        acc = fmaf(h.z, w3col[c+2], acc);
        acc = fmaf(h.w, w3col[c+3], acc);
      }
      sum += acc; sq += acc*acc;
      s23[(p*16 + k)*64 + lane] = (_Float16)acc;
    }
  }
  red[wid][lane]=sum; red[wid][64+lane]=sq;
  __syncthreads();
  if (tid < 128) {
    float v = red[0][tid]+red[1][tid]+red[2][tid]+red[3][tid];
    atomicAdd(&statw[SUM3+tid], v);
  }
}

// ---------------------------------------------------------------------------
// Transposes: nfeat (B,DP,M)->nfeatT (B,M,DP) f32;  feat (B,D,N)->featT (B*N,D) f16
__global__ __launch_bounds__(256) void nfeatT_kernel(const float* __restrict__ nf,
                                                     float* __restrict__ nfT) {
  __shared__ float t[64][65];
  int m0 = blockIdx.x*64, b = blockIdx.y;
  int tid=threadIdx.x, c=tid&63, r4=tid>>6;
  #pragma unroll
  for (int i=0;i<16;i++) {
    int d = i*4 + r4;
    t[d][c] = nf[((size_t)b*DPC + d)*MM + m0 + c];
  }
  __syncthreads();
  #pragma unroll
  for (int i=0;i<16;i++) {
    int m = i*4 + r4;
    nfT[((size_t)b*MM + m0 + m)*64 + c] = t[c][m];
  }
}

__global__ __launch_bounds__(256) void featT_kernel(const float* __restrict__ f,
                                                    _Float16* __restrict__ fT) {
  __shared__ float t[64][65];
  int n0 = blockIdx.x*64, c0 = blockIdx.y*64, b = blockIdx.z;
  int tid=threadIdx.x, c=tid&63, r4=tid>>6;
  #pragma unroll
  for (int i=0;i<16;i++) {
    int d = i*4 + r4;
    t[d][c] = f[((size_t)b*DD + c0 + d)*NN + n0 + c];
  }
  __syncthreads();
  #pragma unroll
  for (int i=0;i<16;i++) {
    int n = i*4 + r4;
    fT[((size_t)b*NN + n0 + n)*128 + c0 + c] = (_Float16)t[c][n];
  }
}

// wf (KTOT x OCC f32) -> wfB: B-fragment order. Fragment (s,t): lane l holds
// k = s*32 + (l>>4)*8 + i,  oc = t*16 + (l&15)  (same lane->k map as A-frags).
__global__ __launch_bounds__(256) void wfb_kernel(const float* __restrict__ wf,
                                                  _Float16* __restrict__ wfB) {
  int s = blockIdx.x, t = blockIdx.y;
  int tid = threadIdx.x;
  int l = tid >> 2, i2 = (tid & 3)*2;
  int k  = s*32 + (l>>4)*8 + i2;
  int oc = t*16 + (l&15);
  float a = wf[(size_t)k*OCC + oc];
  float b = wf[(size_t)(k+1)*OCC + oc];
  half2t h = { (_Float16)a, (_Float16)b };
  *(half2t*)(wfB + (((size_t)s*16 + t)*64 + l)*8 + i2) = h;
}

// ---------------------------------------------------------------------------
// Fused: 32 points/block, 512 thr (8 waves).
// Phase A: wm = relu(affine(s3)) -> packed f16 regs (wave owns 4 pts, lane=w)
// Per 512-k chunk: stage G (coalesced from nfeatT) -> agg -> X f16 (swizzled LDS)
//                  -> mfma f16 16x16x32 (wave: 2 rowtiles x 2 octiles)
__global__ __launch_bounds__(512, 4) void fused2_kernel(
    const float* __restrict__ nfeatT, const _Float16* __restrict__ featT,
    const int* __restrict__ idx, const _Float16* __restrict__ s23,
    const float* __restrict__ stats, const _Float16* __restrict__ wfB,
    _Float16* __restrict__ y16) {
  __shared__ __align__(16) _Float16 Xs[32*512];   // 32 KB, XOR-swizzled rows
  __shared__ __align__(16) float Gs[32*16*8];     // 16 KB
  __shared__ int Js[512];
  int tid=threadIdx.x, lane=tid&63, wid=tid>>6;
  int blk = blockIdx.x;
  int bb = (blk*32) >> 13;                        // batch uniform per block
  Js[tid] = idx[(size_t)blk*512 + tid];

  float sc3 = stats[SC3+lane], sh3 = stats[SH3+lane];
  half2t wm2[4][8];
  #pragma unroll
  for (int pti=0; pti<4; ++pti) {
    size_t p = (size_t)blk*32 + wid*4 + pti;
    #pragma unroll
    for (int k2=0;k2<8;k2++) {
      float va = fmaxf((float)s23[(p*16 + 2*k2  )*64 + lane]*sc3 + sh3, 0.f);
      float vb = fmaxf((float)s23[(p*16 + 2*k2+1)*64 + lane]*sc3 + sh3, 0.f);
      wm2[pti][k2] = half2t{ (_Float16)va, (_Float16)vb };
    }
  }
  __syncthreads();

  int t0 = wid*2, t1 = wid*2+1;
  int lane15 = lane&15, lgrp = lane>>4;
  int rowA0 = lane15, rowA1 = 16 + lane15;
  int swzA = (rowA0 & 7) << 4;                    // rowA1&7 == rowA0&7
  f32x4 acc00={0,0,0,0}, acc01={0,0,0,0}, acc10={0,0,0,0}, acc11={0,0,0,0};
  const char* XsB = (const char*)Xs;
  int sIdx = tid >> 4, sK = tid & 15;             // staging: (pt, k) per thread
  int sRow = sIdx*16 + sK;

  for (int c=0; c<8; ++c) {
    { // stage G chunk: nfeatT[b][j][c*8 .. c*8+8)
      int j = Js[sRow];
      const float* src = nfeatT + ((size_t)bb*MM + j)*64 + c*8;
      float4 v0 = *(const float4*)src;
      float4 v1 = *(const float4*)(src+4);
      float* dst = &Gs[sRow*8];
      *(float4*)dst = v0; *(float4*)(dst+4) = v1;
    }
    __syncthreads();
    // agg: wave's 4 pts, 8 d each, lane = w
    #pragma unroll
    for (int pti=0; pti<4; ++pti) {
      int ptl = wid*4 + pti;
      const float* g = &Gs[ptl*128];
      float a[8] = {0,0,0,0,0,0,0,0};
      #pragma unroll
      for (int k=0;k<16;k++) {
        float4 gA = *(const float4*)(g + k*8);
        float4 gB = *(const float4*)(g + k*8 + 4);
        float wmv = (float)wm2[pti][k>>1][k&1];
        a[0]=fmaf(gA.x,wmv,a[0]); a[1]=fmaf(gA.y,wmv,a[1]);
        a[2]=fmaf(gA.z,wmv,a[2]); a[3]=fmaf(gA.w,wmv,a[3]);
        a[4]=fmaf(gB.x,wmv,a[4]); a[5]=fmaf(gB.y,wmv,a[5]);
        a[6]=fmaf(gB.z,wmv,a[6]); a[7]=fmaf(gB.w,wmv,a[7]);
      }
      int swz = (ptl&7)<<4;
      #pragma unroll
      for (int dl=0; dl<8; ++dl) {
        int off = ptl*1024 + ((dl*64 + lane)<<1);
        *(_Float16*)((char*)Xs + (off ^ swz)) = (_Float16)a[dl];
      }
    }
    __syncthreads();
    // mfma over this chunk's 16 k-steps
    #pragma unroll
    for (int s=0; s<16; ++s) {
      int kb = (s*32 + lgrp*8)*2;
      half8 A0 = *(const half8*)(XsB + ((rowA0*1024 + kb) ^ swzA));
      half8 A1 = *(const half8*)(XsB + ((rowA1*1024 + kb) ^ swzA));
      int sg = c*16 + s;
      half8 B0 = *(const half8*)(wfB + ((size_t)(sg*16 + t0)*64 + lane)*8);
      half8 B1 = *(const half8*)(wfB + ((size_t)(sg*16 + t1)*64 + lane)*8);
      acc00 = __builtin_amdgcn_mfma_f32_16x16x32_f16(A0,B0,acc00,0,0,0);
      acc01 = __builtin_amdgcn_mfma_f32_16x16x32_f16(A0,B1,acc01,0,0,0);
      acc10 = __builtin_amdgcn_mfma_f32_16x16x32_f16(A1,B0,acc10,0,0,0);
      acc11 = __builtin_amdgcn_mfma_f32_16x16x32_f16(A1,B1,acc11,0,0,0);
    }
    __syncthreads();
  }
  { // feature tail: copy featT rows into Xs (128 k)
    int ptl = tid>>4, c8 = (tid&15)*8;
    size_t p = (size_t)blk*32 + ptl;
    half8 v = *(const half8*)(featT + p*128 + c8);
    int swz = (ptl&7)<<4;
    *(half8*)((char*)Xs + ((ptl*1024 + c8*2) ^ swz)) = v;
  }
  __syncthreads();
  #pragma unroll
  for (int s=0; s<4; ++s) {
    int kb = (s*32 + lgrp*8)*2;
    half8 A0 = *(const half8*)(XsB + ((rowA0*1024 + kb) ^ swzA));
    half8 A1 = *(const half8*)(XsB + ((rowA1*1024 + kb) ^ swzA));
    int sg = 128 + s;
    half8 B0 = *(const half8*)(wfB + ((size_t)(sg*16 + t0)*64 + lane)*8);
    half8 B1 = *(const half8*)(wfB + ((size_t)(sg*16 + t1)*64 + lane)*8);
    acc00 = __builtin_amdgcn_mfma_f32_16x16x32_f16(A0,B0,acc00,0,0,0);
    acc01 = __builtin_amdgcn_mfma_f32_16x16x32_f16(A0,B1,acc01,0,0,0);
    acc10 = __builtin_amdgcn_mfma_f32_16x16x32_f16(A1,B0,acc10,0,0,0);
    acc11 = __builtin_amdgcn_mfma_f32_16x16x32_f16(A1,B1,acc11,0,0,0);
  }
  // epilogue: C/D layout col=lane&15, row=(lane>>4)*4+j  [m89]
  #pragma unroll
  for (int j=0;j<4;j++) {
    size_t r0 = (size_t)blk*32 + lgrp*4 + j;
    size_t r1 = r0 + 16;
    y16[r0*256 + t0*16 + lane15] = (_Float16)acc00[j];
    y16[r0*256 + t1*16 + lane15] = (_Float16)acc01[j];
    y16[r1*256 + t0*16 + lane15] = (_Float16)acc10[j];
    y16[r1*256 + t1*16 + lane15] = (_Float16)acc11[j];
  }
}

// ---------------------------------------------------------------------------
__global__ __launch_bounds__(256) void statsf_kernel(const _Float16* __restrict__ y,
                                                     float* __restrict__ stats) {
  int o = threadIdx.x;
  size_t r0 = (size_t)blockIdx.x * 128;
  float sum=0.f, sq=0.f;
  for (int r=0;r<128;r++) {
    float v = (float)y[(r0+r)*256 + o];
    sum += v; sq += v*v;
  }
  atomicAdd(&stats[SUMF+o], sum);
  atomicAdd(&stats[SQF+o], sq);
}

__global__ __launch_bounds__(256) void final_kernel(const _Float16* __restrict__ y,
    const float* __restrict__ stats, float* __restrict__ out) {
  __shared__ float t[64][65];
  int o0 = blockIdx.x*64, n0 = blockIdx.y*64, b = blockIdx.z;
  int tid=threadIdx.x, c=tid&63, r4=tid>>6;
  #pragma unroll
  for (int i=0;i<16;i++) {
    int r = i*4 + r4;
    t[r][c] = (float)y[((size_t)b*NN + n0 + r)*256 + o0 + c];
  }
  __syncthreads();
  #pragma unroll
  for (int i=0;i<16;i++) {
    int orow = i*4 + r4;
    float sc = stats[SCF + o0 + orow], sh = stats[SHF + o0 + orow];
    out[((size_t)b*OCC + o0 + orow)*NN + n0 + c] = fmaxf(t[c][orow]*sc + sh, 0.f);
  }
}

// ---------------------------------------------------------------------------
extern "C" void kernel_launch(void* const* d_in, const int* in_sizes, int n_in,
                              void* d_out, int out_size, void* d_ws, size_t ws_size,
                              hipStream_t stream) {
  const float* xyz   = (const float*)d_in[0];
  const float* nxyz  = (const float*)d_in[1];
  const float* feat  = (const float*)d_in[2];
  const float* nfeat = (const float*)d_in[3];
  const float* w1    = (const float*)d_in[4];
  const float* w2    = (const float*)d_in[5];
  const float* w3    = (const float*)d_in[6];
  const float* g1    = (const float*)d_in[7];
  const float* b1    = (const float*)d_in[8];
  const float* g2    = (const float*)d_in[9];
  const float* b2    = (const float*)d_in[10];
  const float* g3    = (const float*)d_in[11];
  const float* b3    = (const float*)d_in[12];
  const float* wf    = (const float*)d_in[13];
  const float* gf    = (const float*)d_in[14];
  const float* bf    = (const float*)d_in[15];

  char* ws = (char*)d_ws;
  int*      idx    = (int*)(ws + IDX_OFF);
  float*    stats  = (float*)(ws + ST_OFF);
  _Float16* wfB    = (_Float16*)(ws + WFB_OFF);
  float*    nfT    = (float*)(ws + NFT_OFF);
  _Float16* fT     = (_Float16*)(ws + FTT_OFF);
  _Float16* y16    = (_Float16*)(ws + Y16_OFF);
  _Float16* s23    = (_Float16*)(ws + S23_OFF);
  float2*   cand   = (float2*)(ws + CAND_OFF);
  float*    outp   = (float*)d_out;

  hipMemsetAsync(stats, 0, 8192, stream);

  // independent prep
  nfeatT_kernel<<<dim3(MM/64, BB), 256, 0, stream>>>(nfeat, nfT);
  featT_kernel<<<dim3(NN/64, DD/64, BB), 256, 0, stream>>>(feat, fT);
  wfb_kernel<<<dim3(KTOT/32, OCC/16), 256, 0, stream>>>(wf, wfB);

  // knn + bn1
  knn_part<<<dim3(NN/256, 2, BB), 256, 0, stream>>>(xyz, nxyz, cand);
  knn_merge<<<NPTS/256, 256, 0, stream>>>(xyz, nxyz, cand, idx, stats);
  bn1_kernel<<<1, 64, 0, stream>>>(w1, g1, b1, stats);

  // weightnet chain with materialized s2/s3
  k2_kernel<<<NPTS/32, 256, 0, stream>>>(xyz, nxyz, idx, w1, w2, stats, s23, stats);
  bnsmall_kernel<<<1, 64, 0, stream>>>(g2, b2, stats, SUM2, SQ2, SC2, SH2, 1.0f/(float)CNT1);
  k3_kernel<<<NPTS/32, 256, 0, stream>>>(w3, stats, s23, stats);
  bnsmall_kernel<<<1, 64, 0, stream>>>(g3, b3, stats, SUM3, SQ3, SC3, SH3, 1.0f/(float)CNT1);

  // fused agg + final GEMM (MFMA f16)
  fused2_kernel<<<NPTS/32, 512, 0, stream>>>(nfT, fT, idx, s23, stats, wfB, y16);

  // final BN + transpose
  statsf_kernel<<<NPTS/128, 256, 0, stream>>>(y16, stats);
  bnsmall_kernel<<<1, 256, 0, stream>>>(gf, bf, stats, SUMF, SQF, SCF, SHF, 1.0f/(float)NPTS);
  final_kernel<<<dim3(OCC/64, NN/64, BB), 256, 0, stream>>>(y16, stats, outp);
}

// Round 4
// 1113.316 us; speedup vs baseline: 4.4146x; 1.6276x over previous
//
#include <hip/hip_runtime.h>

// Problem constants
#define BB   4
#define NN   8192
#define MM   2048
#define KNNK 16
#define DD   128
#define DPC  64
#define WCC  64
#define OCC  256
#define KTOT 4224          // DPC*WCC + DD
#define EPSV 1e-5f
#define NPTS (BB*NN)       // 32768
#define CNT1 (NPTS*KNNK)   // 524288
#define NSPLIT 8
#define MCAND (MM/NSPLIT)  // 256 candidates per split

// stats region float indices
enum { REL0=0, SC1=16, SH1=80, SUM2=144, SQ2=208, SC2=272, SH2=336,
       SUM3=400, SQ3=464, SC3=528, SH3=592, SUMF=656, SQF=912, SCF=1168, SHF=1424 };

// workspace byte offsets
#define IDX_OFF   0u           // 32768*16*4 = 2 MB
#define ST_OFF    2097152u     // 8 KB
#define WFB_OFF   2105344u     // 132*16*64*8*2 = 2162688
#define NFT_OFF   4268032u     // 4*2048*64*4 = 2 MB
#define FTT_OFF   6365184u     // 32768*128*2 = 8388608
#define Y16_OFF   14753792u    // 32768*256*2 = 16777216
#define S23_OFF   31531008u    // 524288*64*2 = 67108864  (total ~94 MB)
#define CAND_OFF  S23_OFF      // cand (33.5 MB) aliases s23: dead before k2 runs

typedef _Float16 half8 __attribute__((ext_vector_type(8)));
typedef _Float16 half2t __attribute__((ext_vector_type(2)));
typedef float    f32x4 __attribute__((ext_vector_type(4)));

// ---------------------------------------------------------------------------
// KNN over one split (256 candidates). 1024 blocks -> 4 waves/SIMD.
__global__ __launch_bounds__(256) void knn_part8(
    const float* __restrict__ xyz, const float* __restrict__ nxyz,
    float2* __restrict__ cand) {
  __shared__ float4 sc4[MCAND];
  int b = blockIdx.z, h = blockIdx.y;
  int mbase = h * MCAND;
  const float* np_ = nxyz + ((size_t)b*MM + mbase)*3;
  if (threadIdx.x < MCAND) {
    int i = threadIdx.x;
    float x = np_[i*3+0], y = np_[i*3+1], z = np_[i*3+2];
    sc4[i] = make_float4(x, y, z, x*x+y*y+z*z);
  }
  __syncthreads();
  int n = blockIdx.x*256 + threadIdx.x;
  const float* pp = xyz + ((size_t)b*NN + n)*3;
  float px=pp[0], py=pp[1], pz=pp[2];
  float pn = px*px + py*py + pz*pz;
  float dist[KNNK]; int ind[KNNK];
  #pragma unroll
  for (int k=0;k<KNNK;k++){ dist[k]=3.0e38f; ind[k]=0; }
  #pragma unroll 2
  for (int m=0;m<MCAND;m++) {
    float4 c = sc4[m];
    float t = fmaf(px, c.x, fmaf(py, c.y, pz*c.z));
    float d = fmaf(-2.0f, t, pn + c.w);
    if (__any(d < dist[KNNK-1])) {   // strict <: equal keeps earlier index
      float cd = d; int ci = mbase + m;
      #pragma unroll
      for (int j=0;j<KNNK;j++) {
        bool ins = cd < dist[j];
        float nd = ins ? cd : dist[j];
        int   ni = ins ? ci : ind[j];
        cd = ins ? dist[j] : cd;
        ci = ins ? ind[j]  : ci;
        dist[j] = nd; ind[j] = ni;
      }
    }
  }
  float2* op = cand + (((size_t)b*NN + n)*NSPLIT + h)*16;
  #pragma unroll
  for (int k=0;k<KNNK;k++) op[k] = make_float2(dist[k], __int_as_float(ind[k]));
}

// Merge NSPLIT sorted 16-lists -> final idx; accumulate rel first/second moments.
__global__ __launch_bounds__(256) void knn_merge(
    const float* __restrict__ xyz, const float* __restrict__ nxyz,
    const float2* __restrict__ cand, int* __restrict__ idxo,
    float* __restrict__ stats) {
  __shared__ float sred[9];
  if (threadIdx.x < 9) sred[threadIdx.x] = 0.f;
  __syncthreads();
  int p = blockIdx.x*256 + threadIdx.x;
  int b = p >> 13;
  const float2* ca = cand + (size_t)p*(NSPLIT*16);
  float dist[16]; int ind[16];
  #pragma unroll
  for (int k=0;k<16;k++) { float2 f = ca[k]; dist[k]=f.x; ind[k]=__float_as_int(f.y); }
  // splits processed in ascending index range; strict < keeps lower index on ties
  for (int h=1; h<NSPLIT; ++h) {
    #pragma unroll
    for (int k=0;k<16;k++) {
      float2 f = ca[h*16+k];
      float cd = f.x; int ci = __float_as_int(f.y);
      if (__any(cd < dist[15])) {
        #pragma unroll
        for (int j=0;j<16;j++) {
          bool ins = cd < dist[j];
          float nd = ins ? cd : dist[j];
          int   ni = ins ? ci : ind[j];
          cd = ins ? dist[j] : cd;
          ci = ins ? ind[j]  : ci;
          dist[j] = nd; ind[j] = ni;
        }
      }
    }
  }
  const float* pp = xyz + (size_t)p*3;
  float px=pp[0], py=pp[1], pz=pp[2];
  int* op = idxo + (size_t)p*16;
  float s0=0,s1=0,s2=0,s3=0,s4=0,s5=0,s6=0,s7=0,s8=0;
  #pragma unroll
  for (int k=0;k<16;k++) {
    op[k] = ind[k];
    const float* q = nxyz + ((size_t)b*MM + ind[k])*3;
    float rx=q[0]-px, ry=q[1]-py, rz=q[2]-pz;
    s0+=rx; s1+=ry; s2+=rz;
    s3+=rx*rx; s4+=rx*ry; s5+=rx*rz; s6+=ry*ry; s7+=ry*rz; s8+=rz*rz;
  }
  atomicAdd(&sred[0],s0); atomicAdd(&sred[1],s1); atomicAdd(&sred[2],s2);
  atomicAdd(&sred[3],s3); atomicAdd(&sred[4],s4); atomicAdd(&sred[5],s5);
  atomicAdd(&sred[6],s6); atomicAdd(&sred[7],s7); atomicAdd(&sred[8],s8);
  __syncthreads();
  if (threadIdx.x < 9) atomicAdd(&stats[REL0 + threadIdx.x], sred[threadIdx.x]);
}

// ---------------------------------------------------------------------------
// BN1 closed form (s1 linear in rel).
__global__ void bn1_kernel(const float* __restrict__ w1, const float* __restrict__ g1,
                           const float* __restrict__ b1, float* __restrict__ stats) {
  int d = threadIdx.x;
  float inv = 1.0f / (float)CNT1;
  float mx=stats[0]*inv, my=stats[1]*inv, mz=stats[2]*inv;
  float xx=stats[3]*inv, xy=stats[4]*inv, xz=stats[5]*inv,
        yy=stats[6]*inv, yz=stats[7]*inv, zz=stats[8]*inv;
  float wx=w1[0*WCC+d], wy=w1[1*WCC+d], wz=w1[2*WCC+d];
  float m  = mx*wx + my*wy + mz*wz;
  float e2 = wx*wx*xx + wy*wy*yy + wz*wz*zz + 2.0f*(wx*wy*xy + wx*wz*xz + wy*wz*yz);
  float v  = e2 - m*m;
  float sc = rsqrtf(v + EPSV) * g1[d];
  stats[SC1+d] = sc;
  stats[SH1+d] = b1[d] - m*sc;
}

__global__ void bnsmall_kernel(const float* __restrict__ g, const float* __restrict__ b,
                               float* __restrict__ stats, int sumOff, int sqOff,
                               int scOff, int shOff, float inv) {
  int d = threadIdx.x;
  float m = stats[sumOff+d]*inv;
  float v = stats[sqOff+d]*inv - m*m;
  float sc = rsqrtf(v + EPSV) * g[d];
  stats[scOff+d] = sc;
  stats[shOff+d] = b[d] - m*sc;
}

// ---------------------------------------------------------------------------
// K2: rel -> h1 -> s2; BN2 stats; store s2 (f16). 32 pts/block, 8/wave, lane=w.
__global__ __launch_bounds__(256, 4) void k2_kernel(
    const float* __restrict__ xyz, const float* __restrict__ nxyz,
    const int* __restrict__ idx, const float* __restrict__ w1,
    const float* __restrict__ w2, const float* __restrict__ stats,
    _Float16* __restrict__ s23, float* __restrict__ statw) {
  __shared__ __align__(16) float hb[4][KNNK*WCC];
  __shared__ float red[4][128];
  int tid=threadIdx.x, lane=tid&63, wid=tid>>6;
  float w2col[64];
  #pragma unroll
  for (int c=0;c<64;c++) w2col[c] = w2[c*64+lane];
  float w1x=w1[lane], w1y=w1[64+lane], w1z=w1[128+lane];
  float sc1=stats[SC1+lane], sh1=stats[SH1+lane];
  float* hbw = hb[wid];
  float sum=0.f, sq=0.f;
  int pbase = blockIdx.x*32 + wid*8;
  for (int pt=0; pt<8; ++pt) {
    int p = pbase + pt;
    int b = p >> 13;
    const float* pp = xyz + (size_t)p*3;
    float px=pp[0], py=pp[1], pz=pp[2];
    const int* ip = idx + (size_t)p*16;
    #pragma unroll
    for (int k=0;k<16;k++) {
      int j = ip[k];
      const float* q = nxyz + ((size_t)b*MM + j)*3;
      float s1v = (q[0]-px)*w1x + (q[1]-py)*w1y + (q[2]-pz)*w1z;
      hbw[k*64+lane] = fmaxf(s1v*sc1 + sh1, 0.f);
    }
    for (int k=0;k<16;k++) {
      float acc = 0.f;
      #pragma unroll
      for (int c=0;c<64;c+=4) {
        float4 h = *(const float4*)&hbw[k*64+c];
        acc = fmaf(h.x, w2col[c+0], acc);
        acc = fmaf(h.y, w2col[c+1], acc);
        acc = fmaf(h.z, w2col[c+2], acc);
        acc = fmaf(h.w, w2col[c+3], acc);
      }
      sum += acc; sq += acc*acc;
      s23[((size_t)p*16 + k)*64 + lane] = (_Float16)acc;
    }
  }
  red[wid][lane]=sum; red[wid][64+lane]=sq;
  __syncthreads();
  if (tid < 128) {
    float v = red[0][tid]+red[1][tid]+red[2][tid]+red[3][tid];
    atomicAdd(&statw[SUM2+tid], v);   // SQ2 = SUM2+64, contiguous
  }
}

// K3: s2 -> h2 -> s3 (in place); BN3 stats.
__global__ __launch_bounds__(256, 4) void k3_kernel(
    const float* __restrict__ w3, const float* __restrict__ stats,
    _Float16* __restrict__ s23, float* __restrict__ statw) {
  __shared__ __align__(16) float hb[4][KNNK*WCC];
  __shared__ float red[4][128];
  int tid=threadIdx.x, lane=tid&63, wid=tid>>6;
  float w3col[64];
  #pragma unroll
  for (int c=0;c<64;c++) w3col[c] = w3[c*64+lane];
  float sc2=stats[SC2+lane], sh2=stats[SH2+lane];
  float* hbw = hb[wid];
  float sum=0.f, sq=0.f;
  int pbase = blockIdx.x*32 + wid*8;
  for (int pt=0; pt<8; ++pt) {
    size_t p = pbase + pt;
    #pragma unroll
    for (int k=0;k<16;k++) {
      float v = (float)s23[(p*16 + k)*64 + lane];
      hbw[k*64+lane] = fmaxf(v*sc2 + sh2, 0.f);
    }
    for (int k=0;k<16;k++) {
      float acc = 0.f;
      #pragma unroll
      for (int c=0;c<64;c+=4) {
        float4 h = *(const float4*)&hbw[k*64+c];
        acc = fmaf(h.x, w3col[c+0], acc);
        acc = fmaf(h.y, w3col[c+1], acc);
        acc = fmaf(h.z, w3col[c+2], acc);
        acc = fmaf(h.w, w3col[c+3], acc);
      }
      sum += acc; sq += acc*acc;
      s23[(p*16 + k)*64 + lane] = (_Float16)acc;
    }
  }
  red[wid][lane]=sum; red[wid][64+lane]=sq;
  __syncthreads();
  if (tid < 128) {
    float v = red[0][tid]+red[1][tid]+red[2][tid]+red[3][tid];
    atomicAdd(&statw[SUM3+tid], v);
  }
}

// ---------------------------------------------------------------------------
// Transposes: nfeat (B,DP,M)->nfeatT (B,M,DP) f32;  feat (B,D,N)->featT (B*N,D) f16
__global__ __launch_bounds__(256) void nfeatT_kernel(const float* __restrict__ nf,
                                                     float* __restrict__ nfT) {
  __shared__ float t[64][65];
  int m0 = blockIdx.x*64, b = blockIdx.y;
  int tid=threadIdx.x, c=tid&63, r4=tid>>6;
  #pragma unroll
  for (int i=0;i<16;i++) {
    int d = i*4 + r4;
    t[d][c] = nf[((size_t)b*DPC + d)*MM + m0 + c];
  }
  __syncthreads();
  #pragma unroll
  for (int i=0;i<16;i++) {
    int m = i*4 + r4;
    nfT[((size_t)b*MM + m0 + m)*64 + c] = t[c][m];
  }
}

__global__ __launch_bounds__(256) void featT_kernel(const float* __restrict__ f,
                                                    _Float16* __restrict__ fT) {
  __shared__ float t[64][65];
  int n0 = blockIdx.x*64, c0 = blockIdx.y*64, b = blockIdx.z;
  int tid=threadIdx.x, c=tid&63, r4=tid>>6;
  #pragma unroll
  for (int i=0;i<16;i++) {
    int d = i*4 + r4;
    t[d][c] = f[((size_t)b*DD + c0 + d)*NN + n0 + c];
  }
  __syncthreads();
  #pragma unroll
  for (int i=0;i<16;i++) {
    int n = i*4 + r4;
    fT[((size_t)b*NN + n0 + n)*128 + c0 + c] = (_Float16)t[c][n];
  }
}

// wf (KTOT x OCC f32) -> wfB: B-fragment order. Fragment (s,t): lane l holds
// k = s*32 + (l>>4)*8 + i,  oc = t*16 + (l&15)  (same lane->k map as A-frags).
__global__ __launch_bounds__(256) void wfb_kernel(const float* __restrict__ wf,
                                                  _Float16* __restrict__ wfB) {
  int s = blockIdx.x, t = blockIdx.y;
  int tid = threadIdx.x;
  int l = tid >> 2, i2 = (tid & 3)*2;
  int k  = s*32 + (l>>4)*8 + i2;
  int oc = t*16 + (l&15);
  float a = wf[(size_t)k*OCC + oc];
  float b = wf[(size_t)(k+1)*OCC + oc];
  half2t h = { (_Float16)a, (_Float16)b };
  *(half2t*)(wfB + (((size_t)s*16 + t)*64 + l)*8 + i2) = h;
}

// ---------------------------------------------------------------------------
// Fused: 32 points/block, 512 thr (8 waves).
// Phase A: wm = relu(affine(s3)) -> packed f16 regs (wave owns 4 pts, lane=w)
// Per 512-k chunk: stage G (coalesced from nfeatT) -> agg -> X f16 (swizzled LDS)
//                  -> mfma f16 16x16x32 (wave: 2 rowtiles x 2 octiles)
__global__ __launch_bounds__(512, 4) void fused2_kernel(
    const float* __restrict__ nfeatT, const _Float16* __restrict__ featT,
    const int* __restrict__ idx, const _Float16* __restrict__ s23,
    const float* __restrict__ stats, const _Float16* __restrict__ wfB,
    _Float16* __restrict__ y16) {
  __shared__ __align__(16) _Float16 Xs[32*512];   // 32 KB, XOR-swizzled rows
  __shared__ __align__(16) float Gs[32*16*8];     // 16 KB
  __shared__ int Js[512];
  int tid=threadIdx.x, lane=tid&63, wid=tid>>6;
  int blk = blockIdx.x;
  int bb = (blk*32) >> 13;                        // batch uniform per block
  Js[tid] = idx[(size_t)blk*512 + tid];

  float sc3 = stats[SC3+lane], sh3 = stats[SH3+lane];
  half2t wm2[4][8];
  #pragma unroll
  for (int pti=0; pti<4; ++pti) {
    size_t p = (size_t)blk*32 + wid*4 + pti;
    #pragma unroll
    for (int k2=0;k2<8;k2++) {
      float va = fmaxf((float)s23[(p*16 + 2*k2  )*64 + lane]*sc3 + sh3, 0.f);
      float vb = fmaxf((float)s23[(p*16 + 2*k2+1)*64 + lane]*sc3 + sh3, 0.f);
      wm2[pti][k2] = half2t{ (_Float16)va, (_Float16)vb };
    }
  }
  __syncthreads();

  int t0 = wid*2, t1 = wid*2+1;
  int lane15 = lane&15, lgrp = lane>>4;
  int rowA0 = lane15, rowA1 = 16 + lane15;
  int swzA = (rowA0 & 7) << 4;                    // rowA1&7 == rowA0&7
  f32x4 acc00={0,0,0,0}, acc01={0,0,0,0}, acc10={0,0,0,0}, acc11={0,0,0,0};
  const char* XsB = (const char*)Xs;
  int sIdx = tid >> 4, sK = tid & 15;             // staging: (pt, k) per thread
  int sRow = sIdx*16 + sK;

  for (int c=0; c<8; ++c) {
    { // stage G chunk: nfeatT[b][j][c*8 .. c*8+8)
      int j = Js[sRow];
      const float* src = nfeatT + ((size_t)bb*MM + j)*64 + c*8;
      float4 v0 = *(const float4*)src;
      float4 v1 = *(const float4*)(src+4);
      float* dst = &Gs[sRow*8];
      *(float4*)dst = v0; *(float4*)(dst+4) = v1;
    }
    __syncthreads();
    // agg: wave's 4 pts, 8 d each, lane = w
    #pragma unroll
    for (int pti=0; pti<4; ++pti) {
      int ptl = wid*4 + pti;
      const float* g = &Gs[ptl*128];
      float a[8] = {0,0,0,0,0,0,0,0};
      #pragma unroll
      for (int k=0;k<16;k++) {
        float4 gA = *(const float4*)(g + k*8);
        float4 gB = *(const float4*)(g + k*8 + 4);
        float wmv = (float)wm2[pti][k>>1][k&1];
        a[0]=fmaf(gA.x,wmv,a[0]); a[1]=fmaf(gA.y,wmv,a[1]);
        a[2]=fmaf(gA.z,wmv,a[2]); a[3]=fmaf(gA.w,wmv,a[3]);
        a[4]=fmaf(gB.x,wmv,a[4]); a[5]=fmaf(gB.y,wmv,a[5]);
        a[6]=fmaf(gB.z,wmv,a[6]); a[7]=fmaf(gB.w,wmv,a[7]);
      }
      int swz = (ptl&7)<<4;
      #pragma unroll
      for (int dl=0; dl<8; ++dl) {
        int off = ptl*1024 + ((dl*64 + lane)<<1);
        *(_Float16*)((char*)Xs + (off ^ swz)) = (_Float16)a[dl];
      }
    }
    __syncthreads();
    // mfma over this chunk's 16 k-steps
    #pragma unroll
    for (int s=0; s<16; ++s) {
      int kb = (s*32 + lgrp*8)*2;
      half8 A0 = *(const half8*)(XsB + ((rowA0*1024 + kb) ^ swzA));
      half8 A1 = *(const half8*)(XsB + ((rowA1*1024 + kb) ^ swzA));
      int sg = c*16 + s;
      half8 B0 = *(const half8*)(wfB + ((size_t)(sg*16 + t0)*64 + lane)*8);
      half8 B1 = *(const half8*)(wfB + ((size_t)(sg*16 + t1)*64 + lane)*8);
      acc00 = __builtin_amdgcn_mfma_f32_16x16x32_f16(A0,B0,acc00,0,0,0);
      acc01 = __builtin_amdgcn_mfma_f32_16x16x32_f16(A0,B1,acc01,0,0,0);
      acc10 = __builtin_amdgcn_mfma_f32_16x16x32_f16(A1,B0,acc10,0,0,0);
      acc11 = __builtin_amdgcn_mfma_f32_16x16x32_f16(A1,B1,acc11,0,0,0);
    }
    __syncthreads();
  }
  { // feature tail: copy featT rows into Xs (128 k)
    int ptl = tid>>4, c8 = (tid&15)*8;
    size_t p = (size_t)blk*32 + ptl;
    half8 v = *(const half8*)(featT + p*128 + c8);
    int swz = (ptl&7)<<4;
    *(half8*)((char*)Xs + ((ptl*1024 + c8*2) ^ swz)) = v;
  }
  __syncthreads();
  #pragma unroll
  for (int s=0; s<4; ++s) {
    int kb = (s*32 + lgrp*8)*2;
    half8 A0 = *(const half8*)(XsB + ((rowA0*1024 + kb) ^ swzA));
    half8 A1 = *(const half8*)(XsB + ((rowA1*1024 + kb) ^ swzA));
    int sg = 128 + s;
    half8 B0 = *(const half8*)(wfB + ((size_t)(sg*16 + t0)*64 + lane)*8);
    half8 B1 = *(const half8*)(wfB + ((size_t)(sg*16 + t1)*64 + lane)*8);
    acc00 = __builtin_amdgcn_mfma_f32_16x16x32_f16(A0,B0,acc00,0,0,0);
    acc01 = __builtin_amdgcn_mfma_f32_16x16x32_f16(A0,B1,acc01,0,0,0);
    acc10 = __builtin_amdgcn_mfma_f32_16x16x32_f16(A1,B0,acc10,0,0,0);
    acc11 = __builtin_amdgcn_mfma_f32_16x16x32_f16(A1,B1,acc11,0,0,0);
  }
  // epilogue: C/D layout col=lane&15, row=(lane>>4)*4+j  [m89]
  #pragma unroll
  for (int j=0;j<4;j++) {
    size_t r0 = (size_t)blk*32 + lgrp*4 + j;
    size_t r1 = r0 + 16;
    y16[r0*256 + t0*16 + lane15] = (_Float16)acc00[j];
    y16[r0*256 + t1*16 + lane15] = (_Float16)acc01[j];
    y16[r1*256 + t0*16 + lane15] = (_Float16)acc10[j];
    y16[r1*256 + t1*16 + lane15] = (_Float16)acc11[j];
  }
}

// ---------------------------------------------------------------------------
__global__ __launch_bounds__(256) void statsf_kernel(const _Float16* __restrict__ y,
                                                     float* __restrict__ stats) {
  int o = threadIdx.x;
  size_t r0 = (size_t)blockIdx.x * 128;
  float sum=0.f, sq=0.f;
  for (int r=0;r<128;r++) {
    float v = (float)y[(r0+r)*256 + o];
    sum += v; sq += v*v;
  }
  atomicAdd(&stats[SUMF+o], sum);
  atomicAdd(&stats[SQF+o], sq);
}

__global__ __launch_bounds__(256) void final_kernel(const _Float16* __restrict__ y,
    const float* __restrict__ stats, float* __restrict__ out) {
  __shared__ float t[64][65];
  int o0 = blockIdx.x*64, n0 = blockIdx.y*64, b = blockIdx.z;
  int tid=threadIdx.x, c=tid&63, r4=tid>>6;
  #pragma unroll
  for (int i=0;i<16;i++) {
    int r = i*4 + r4;
    t[r][c] = (float)y[((size_t)b*NN + n0 + r)*256 + o0 + c];
  }
  __syncthreads();
  #pragma unroll
  for (int i=0;i<16;i++) {
    int orow = i*4 + r4;
    float sc = stats[SCF + o0 + orow], sh = stats[SHF + o0 + orow];
    out[((size_t)b*OCC + o0 + orow)*NN + n0 + c] = fmaxf(t[c][orow]*sc + sh, 0.f);
  }
}

// ---------------------------------------------------------------------------
extern "C" void kernel_launch(void* const* d_in, const int* in_sizes, int n_in,
                              void* d_out, int out_size, void* d_ws, size_t ws_size,
                              hipStream_t stream) {
  const float* xyz   = (const float*)d_in[0];
  const float* nxyz  = (const float*)d_in[1];
  const float* feat  = (const float*)d_in[2];
  const float* nfeat = (const float*)d_in[3];
  const float* w1    = (const float*)d_in[4];
  const float* w2    = (const float*)d_in[5];
  const float* w3    = (const float*)d_in[6];
  const float* g1    = (const float*)d_in[7];
  const float* b1    = (const float*)d_in[8];
  const float* g2    = (const float*)d_in[9];
  const float* b2    = (const float*)d_in[10];
  const float* g3    = (const float*)d_in[11];
  const float* b3    = (const float*)d_in[12];
  const float* wf    = (const float*)d_in[13];
  const float* gf    = (const float*)d_in[14];
  const float* bf    = (const float*)d_in[15];

  char* ws = (char*)d_ws;
  int*      idx    = (int*)(ws + IDX_OFF);
  float*    stats  = (float*)(ws + ST_OFF);
  _Float16* wfB    = (_Float16*)(ws + WFB_OFF);
  float*    nfT    = (float*)(ws + NFT_OFF);
  _Float16* fT     = (_Float16*)(ws + FTT_OFF);
  _Float16* y16    = (_Float16*)(ws + Y16_OFF);
  _Float16* s23    = (_Float16*)(ws + S23_OFF);
  float2*   cand   = (float2*)(ws + CAND_OFF);
  float*    outp   = (float*)d_out;

  hipMemsetAsync(stats, 0, 8192, stream);

  // independent prep
  nfeatT_kernel<<<dim3(MM/64, BB), 256, 0, stream>>>(nfeat, nfT);
  featT_kernel<<<dim3(NN/64, DD/64, BB), 256, 0, stream>>>(feat, fT);
  wfb_kernel<<<dim3(KTOT/32, OCC/16), 256, 0, stream>>>(wf, wfB);

  // knn + bn1
  knn_part8<<<dim3(NN/256, NSPLIT, BB), 256, 0, stream>>>(xyz, nxyz, cand);
  knn_merge<<<NPTS/256, 256, 0, stream>>>(xyz, nxyz, cand, idx, stats);
  bn1_kernel<<<1, 64, 0, stream>>>(w1, g1, b1, stats);

  // weightnet chain with materialized s2/s3
  k2_kernel<<<NPTS/32, 256, 0, stream>>>(xyz, nxyz, idx, w1, w2, stats, s23, stats);
  bnsmall_kernel<<<1, 64, 0, stream>>>(g2, b2, stats, SUM2, SQ2, SC2, SH2, 1.0f/(float)CNT1);
  k3_kernel<<<NPTS/32, 256, 0, stream>>>(w3, stats, s23, stats);
  bnsmall_kernel<<<1, 64, 0, stream>>>(g3, b3, stats, SUM3, SQ3, SC3, SH3, 1.0f/(float)CNT1);

  // fused agg + final GEMM (MFMA f16)
  fused2_kernel<<<NPTS/32, 512, 0, stream>>>(nfT, fT, idx, s23, stats, wfB, y16);

  // final BN + transpose
  statsf_kernel<<<NPTS/128, 256, 0, stream>>>(y16, stats);
  bnsmall_kernel<<<1, 256, 0, stream>>>(gf, bf, stats, SUMF, SQF, SCF, SHF, 1.0f/(float)NPTS);
  final_kernel<<<dim3(OCC/64, NN/64, BB), 256, 0, stream>>>(y16, stats, outp);
}

// Round 5
// 1001.636 us; speedup vs baseline: 4.9068x; 1.1115x over previous
//
#include <hip/hip_runtime.h>

// Problem constants
#define BB   4
#define NN   8192
#define MM   2048
#define KNNK 16
#define DD   128
#define DPC  64
#define WCC  64
#define OCC  256
#define KTOT 4224          // DPC*WCC + DD
#define EPSV 1e-5f
#define NPTS (BB*NN)       // 32768
#define CNT1 (NPTS*KNNK)   // 524288
#define NSPLIT 8
#define MCAND (MM/NSPLIT)  // 256 candidates per split

// stats region float indices
enum { REL0=0, SC1=16, SH1=80, SUM2=144, SQ2=208, SC2=272, SH2=336,
       SUM3=400, SQ3=464, SC3=528, SH3=592, SUMF=656, SQF=912, SCF=1168, SHF=1424 };

// workspace byte offsets
#define IDX_OFF   0u           // 32768*16*4 = 2 MB
#define ST_OFF    2097152u     // 8 KB
#define WFB_OFF   2105344u     // 132*16*64*8*2 = 2162688
#define NFT_OFF   4268032u     // 4*2048*64*2 = 1 MB (f16 now)
#define FTT_OFF   5316608u     // 32768*128*2 = 8388608
#define Y16_OFF   13705216u    // 32768*256*2 = 16777216
#define S23_OFF   30482432u    // 524288*64*2 = 67108864  (total ~97.6 MB)
#define CAND_OFF  S23_OFF      // cand (33.5 MB) aliases s23: dead before k2 runs

typedef _Float16 half8 __attribute__((ext_vector_type(8)));
typedef _Float16 half2t __attribute__((ext_vector_type(2)));
typedef float    f32x4 __attribute__((ext_vector_type(4)));

#if __has_builtin(__builtin_amdgcn_fdot2)
__device__ __forceinline__ float fdot2f(half2t a, half2t b, float c) {
  return __builtin_amdgcn_fdot2(a, b, c, false);
}
#else
__device__ __forceinline__ float fdot2f(half2t a, half2t b, float c) {
  return c + (float)a[0]*(float)b[0] + (float)a[1]*(float)b[1];
}
#endif

// ---------------------------------------------------------------------------
// KNN over one split (256 candidates). 1024 blocks -> 4 waves/SIMD.
__global__ __launch_bounds__(256) void knn_part8(
    const float* __restrict__ xyz, const float* __restrict__ nxyz,
    float2* __restrict__ cand) {
  __shared__ float4 sc4[MCAND];
  int b = blockIdx.z, h = blockIdx.y;
  int mbase = h * MCAND;
  const float* np_ = nxyz + ((size_t)b*MM + mbase)*3;
  if (threadIdx.x < MCAND) {
    int i = threadIdx.x;
    float x = np_[i*3+0], y = np_[i*3+1], z = np_[i*3+2];
    sc4[i] = make_float4(x, y, z, x*x+y*y+z*z);
  }
  __syncthreads();
  int n = blockIdx.x*256 + threadIdx.x;
  const float* pp = xyz + ((size_t)b*NN + n)*3;
  float px=pp[0], py=pp[1], pz=pp[2];
  float pn = px*px + py*py + pz*pz;
  float dist[KNNK]; int ind[KNNK];
  #pragma unroll
  for (int k=0;k<KNNK;k++){ dist[k]=3.0e38f; ind[k]=0; }
  #pragma unroll 2
  for (int m=0;m<MCAND;m++) {
    float4 c = sc4[m];
    float t = fmaf(px, c.x, fmaf(py, c.y, pz*c.z));
    float d = fmaf(-2.0f, t, pn + c.w);
    if (__any(d < dist[KNNK-1])) {   // strict <: equal keeps earlier index
      float cd = d; int ci = mbase + m;
      #pragma unroll
      for (int j=0;j<KNNK;j++) {
        bool ins = cd < dist[j];
        float nd = ins ? cd : dist[j];
        int   ni = ins ? ci : ind[j];
        cd = ins ? dist[j] : cd;
        ci = ins ? ind[j]  : ci;
        dist[j] = nd; ind[j] = ni;
      }
    }
  }
  float2* op = cand + (((size_t)b*NN + n)*NSPLIT + h)*16;
  #pragma unroll
  for (int k=0;k<KNNK;k++) op[k] = make_float2(dist[k], __int_as_float(ind[k]));
}

// Merge NSPLIT sorted 16-lists -> final idx; accumulate rel first/second moments.
__global__ __launch_bounds__(256) void knn_merge(
    const float* __restrict__ xyz, const float* __restrict__ nxyz,
    const float2* __restrict__ cand, int* __restrict__ idxo,
    float* __restrict__ stats) {
  __shared__ float sred[9];
  if (threadIdx.x < 9) sred[threadIdx.x] = 0.f;
  __syncthreads();
  int p = blockIdx.x*256 + threadIdx.x;
  int b = p >> 13;
  const float2* ca = cand + (size_t)p*(NSPLIT*16);
  float dist[16]; int ind[16];
  #pragma unroll
  for (int k=0;k<16;k++) { float2 f = ca[k]; dist[k]=f.x; ind[k]=__float_as_int(f.y); }
  // splits processed in ascending index range; strict < keeps lower index on ties
  for (int h=1; h<NSPLIT; ++h) {
    #pragma unroll
    for (int k=0;k<16;k++) {
      float2 f = ca[h*16+k];
      float cd = f.x; int ci = __float_as_int(f.y);
      if (__any(cd < dist[15])) {
        #pragma unroll
        for (int j=0;j<16;j++) {
          bool ins = cd < dist[j];
          float nd = ins ? cd : dist[j];
          int   ni = ins ? ci : ind[j];
          cd = ins ? dist[j] : cd;
          ci = ins ? ind[j]  : ci;
          dist[j] = nd; ind[j] = ni;
        }
      }
    }
  }
  const float* pp = xyz + (size_t)p*3;
  float px=pp[0], py=pp[1], pz=pp[2];
  int* op = idxo + (size_t)p*16;
  float s0=0,s1=0,s2=0,s3=0,s4=0,s5=0,s6=0,s7=0,s8=0;
  #pragma unroll
  for (int k=0;k<16;k++) {
    op[k] = ind[k];
    const float* q = nxyz + ((size_t)b*MM + ind[k])*3;
    float rx=q[0]-px, ry=q[1]-py, rz=q[2]-pz;
    s0+=rx; s1+=ry; s2+=rz;
    s3+=rx*rx; s4+=rx*ry; s5+=rx*rz; s6+=ry*ry; s7+=ry*rz; s8+=rz*rz;
  }
  atomicAdd(&sred[0],s0); atomicAdd(&sred[1],s1); atomicAdd(&sred[2],s2);
  atomicAdd(&sred[3],s3); atomicAdd(&sred[4],s4); atomicAdd(&sred[5],s5);
  atomicAdd(&sred[6],s6); atomicAdd(&sred[7],s7); atomicAdd(&sred[8],s8);
  __syncthreads();
  if (threadIdx.x < 9) atomicAdd(&stats[REL0 + threadIdx.x], sred[threadIdx.x]);
}

// ---------------------------------------------------------------------------
// BN1 closed form (s1 linear in rel).
__global__ void bn1_kernel(const float* __restrict__ w1, const float* __restrict__ g1,
                           const float* __restrict__ b1, float* __restrict__ stats) {
  int d = threadIdx.x;
  float inv = 1.0f / (float)CNT1;
  float mx=stats[0]*inv, my=stats[1]*inv, mz=stats[2]*inv;
  float xx=stats[3]*inv, xy=stats[4]*inv, xz=stats[5]*inv,
        yy=stats[6]*inv, yz=stats[7]*inv, zz=stats[8]*inv;
  float wx=w1[0*WCC+d], wy=w1[1*WCC+d], wz=w1[2*WCC+d];
  float m  = mx*wx + my*wy + mz*wz;
  float e2 = wx*wx*xx + wy*wy*yy + wz*wz*zz + 2.0f*(wx*wy*xy + wx*wz*xz + wy*wz*yz);
  float v  = e2 - m*m;
  float sc = rsqrtf(v + EPSV) * g1[d];
  stats[SC1+d] = sc;
  stats[SH1+d] = b1[d] - m*sc;
}

__global__ void bnsmall_kernel(const float* __restrict__ g, const float* __restrict__ b,
                               float* __restrict__ stats, int sumOff, int sqOff,
                               int scOff, int shOff, float inv) {
  int d = threadIdx.x;
  float m = stats[sumOff+d]*inv;
  float v = stats[sqOff+d]*inv - m*m;
  float sc = rsqrtf(v + EPSV) * g[d];
  stats[scOff+d] = sc;
  stats[shOff+d] = b[d] - m*sc;
}

// ---------------------------------------------------------------------------
// K2: rel -> h1 -> s2; BN2 stats; store s2 (f16). 32 pts/block, 8/wave, lane=w.
__global__ __launch_bounds__(256, 4) void k2_kernel(
    const float* __restrict__ xyz, const float* __restrict__ nxyz,
    const int* __restrict__ idx, const float* __restrict__ w1,
    const float* __restrict__ w2, const float* __restrict__ stats,
    _Float16* __restrict__ s23, float* __restrict__ statw) {
  __shared__ __align__(16) float hb[4][KNNK*WCC];
  __shared__ float red[4][128];
  int tid=threadIdx.x, lane=tid&63, wid=tid>>6;
  float w2col[64];
  #pragma unroll
  for (int c=0;c<64;c++) w2col[c] = w2[c*64+lane];
  float w1x=w1[lane], w1y=w1[64+lane], w1z=w1[128+lane];
  float sc1=stats[SC1+lane], sh1=stats[SH1+lane];
  float* hbw = hb[wid];
  float sum=0.f, sq=0.f;
  int pbase = blockIdx.x*32 + wid*8;
  for (int pt=0; pt<8; ++pt) {
    int p = pbase + pt;
    int b = p >> 13;
    const float* pp = xyz + (size_t)p*3;
    float px=pp[0], py=pp[1], pz=pp[2];
    const int* ip = idx + (size_t)p*16;
    #pragma unroll
    for (int k=0;k<16;k++) {
      int j = ip[k];
      const float* q = nxyz + ((size_t)b*MM + j)*3;
      float s1v = (q[0]-px)*w1x + (q[1]-py)*w1y + (q[2]-pz)*w1z;
      hbw[k*64+lane] = fmaxf(s1v*sc1 + sh1, 0.f);
    }
    for (int k=0;k<16;k++) {
      float acc = 0.f;
      #pragma unroll
      for (int c=0;c<64;c+=4) {
        float4 h = *(const float4*)&hbw[k*64+c];
        acc = fmaf(h.x, w2col[c+0], acc);
        acc = fmaf(h.y, w2col[c+1], acc);
        acc = fmaf(h.z, w2col[c+2], acc);
        acc = fmaf(h.w, w2col[c+3], acc);
      }
      sum += acc; sq += acc*acc;
      s23[((size_t)p*16 + k)*64 + lane] = (_Float16)acc;
    }
  }
  red[wid][lane]=sum; red[wid][64+lane]=sq;
  __syncthreads();
  if (tid < 128) {
    float v = red[0][tid]+red[1][tid]+red[2][tid]+red[3][tid];
    atomicAdd(&statw[SUM2+tid], v);   // SQ2 = SUM2+64, contiguous
  }
}

// K3: s2 -> h2 -> s3 (in place); BN3 stats.
__global__ __launch_bounds__(256, 4) void k3_kernel(
    const float* __restrict__ w3, const float* __restrict__ stats,
    _Float16* __restrict__ s23, float* __restrict__ statw) {
  __shared__ __align__(16) float hb[4][KNNK*WCC];
  __shared__ float red[4][128];
  int tid=threadIdx.x, lane=tid&63, wid=tid>>6;
  float w3col[64];
  #pragma unroll
  for (int c=0;c<64;c++) w3col[c] = w3[c*64+lane];
  float sc2=stats[SC2+lane], sh2=stats[SH2+lane];
  float* hbw = hb[wid];
  float sum=0.f, sq=0.f;
  int pbase = blockIdx.x*32 + wid*8;
  for (int pt=0; pt<8; ++pt) {
    size_t p = pbase + pt;
    #pragma unroll
    for (int k=0;k<16;k++) {
      float v = (float)s23[(p*16 + k)*64 + lane];
      hbw[k*64+lane] = fmaxf(v*sc2 + sh2, 0.f);
    }
    for (int k=0;k<16;k++) {
      float acc = 0.f;
      #pragma unroll
      for (int c=0;c<64;c+=4) {
        float4 h = *(const float4*)&hbw[k*64+c];
        acc = fmaf(h.x, w3col[c+0], acc);
        acc = fmaf(h.y, w3col[c+1], acc);
        acc = fmaf(h.z, w3col[c+2], acc);
        acc = fmaf(h.w, w3col[c+3], acc);
      }
      sum += acc; sq += acc*acc;
      s23[(p*16 + k)*64 + lane] = (_Float16)acc;
    }
  }
  red[wid][lane]=sum; red[wid][64+lane]=sq;
  __syncthreads();
  if (tid < 128) {
    float v = red[0][tid]+red[1][tid]+red[2][tid]+red[3][tid];
    atomicAdd(&statw[SUM3+tid], v);
  }
}

// ---------------------------------------------------------------------------
// Transposes: nfeat (B,DP,M)->nfeatT (B,M,DP) f16;  feat (B,D,N)->featT (B*N,D) f16
__global__ __launch_bounds__(256) void nfeatT_kernel(const float* __restrict__ nf,
                                                     _Float16* __restrict__ nfT) {
  __shared__ float t[64][65];
  int m0 = blockIdx.x*64, b = blockIdx.y;
  int tid=threadIdx.x, c=tid&63, r4=tid>>6;
  #pragma unroll
  for (int i=0;i<16;i++) {
    int d = i*4 + r4;
    t[d][c] = nf[((size_t)b*DPC + d)*MM + m0 + c];
  }
  __syncthreads();
  #pragma unroll
  for (int i=0;i<16;i++) {
    int m = i*4 + r4;
    nfT[((size_t)b*MM + m0 + m)*64 + c] = (_Float16)t[c][m];
  }
}

__global__ __launch_bounds__(256) void featT_kernel(const float* __restrict__ f,
                                                    _Float16* __restrict__ fT) {
  __shared__ float t[64][65];
  int n0 = blockIdx.x*64, c0 = blockIdx.y*64, b = blockIdx.z;
  int tid=threadIdx.x, c=tid&63, r4=tid>>6;
  #pragma unroll
  for (int i=0;i<16;i++) {
    int d = i*4 + r4;
    t[d][c] = f[((size_t)b*DD + c0 + d)*NN + n0 + c];
  }
  __syncthreads();
  #pragma unroll
  for (int i=0;i<16;i++) {
    int n = i*4 + r4;
    fT[((size_t)b*NN + n0 + n)*128 + c0 + c] = (_Float16)t[c][n];
  }
}

// wf (KTOT x OCC f32) -> wfB: B-fragment order. Fragment (s,t): lane l holds
// k = s*32 + (l>>4)*8 + i,  oc = t*16 + (l&15)  (same lane->k map as A-frags).
__global__ __launch_bounds__(256) void wfb_kernel(const float* __restrict__ wf,
                                                  _Float16* __restrict__ wfB) {
  int s = blockIdx.x, t = blockIdx.y;
  int tid = threadIdx.x;
  int l = tid >> 2, i2 = (tid & 3)*2;
  int k  = s*32 + (l>>4)*8 + i2;
  int oc = t*16 + (l&15);
  float a = wf[(size_t)k*OCC + oc];
  float b = wf[(size_t)(k+1)*OCC + oc];
  half2t h = { (_Float16)a, (_Float16)b };
  *(half2t*)(wfB + (((size_t)s*16 + t)*64 + l)*8 + i2) = h;
}

// ---------------------------------------------------------------------------
// Fused: 32 points/block, 512 thr (8 waves). XCD-swizzled blockIdx.
// Phase A: wm = relu(affine(s3)) -> packed f16 regs (wave owns 4 pts, lane=w)
// Per 512-k chunk: agg (fdot2 from col-major f16 Gs) -> X f16 (swizzled LDS),
//   async-staged Gs double buffer, -> mfma f16 16x16x32 vs prepacked wfB.
__global__ __launch_bounds__(512, 4) void fused2_kernel(
    const _Float16* __restrict__ nfeatT, const _Float16* __restrict__ featT,
    const int* __restrict__ idx, const _Float16* __restrict__ s23,
    const float* __restrict__ stats, const _Float16* __restrict__ wfB,
    _Float16* __restrict__ y16) {
  __shared__ __align__(16) _Float16 Xs[32*512];      // 32 KB, XOR-swizzled rows
  __shared__ __align__(16) _Float16 Gs[2][8][512];   // 16 KB, col-major [d][ptk]
  __shared__ int Js[512];
  int tid=threadIdx.x, lane=tid&63, wid=tid>>6;
  int blk = ((blockIdx.x & 7) << 7) | (blockIdx.x >> 3);   // XCD swizzle (1024%8==0)
  int bb = (blk*32) >> 13;                        // batch uniform per block
  Js[tid] = idx[(size_t)blk*512 + tid];

  float sc3 = stats[SC3+lane], sh3 = stats[SH3+lane];
  half2t wm2[4][8];
  #pragma unroll
  for (int pti=0; pti<4; ++pti) {
    size_t p = (size_t)blk*32 + wid*4 + pti;
    #pragma unroll
    for (int k2=0;k2<8;k2++) {
      float va = fmaxf((float)s23[(p*16 + 2*k2  )*64 + lane]*sc3 + sh3, 0.f);
      float vb = fmaxf((float)s23[(p*16 + 2*k2+1)*64 + lane]*sc3 + sh3, 0.f);
      wm2[pti][k2] = half2t{ (_Float16)va, (_Float16)vb };
    }
  }
  __syncthreads();      // Js visible
  // stage chunk 0 (thread = (pt,k) pair = tid)
  {
    int j = Js[tid];
    half8 gv = *(const half8*)(nfeatT + ((size_t)bb*MM + j)*64);
    #pragma unroll
    for (int dl=0;dl<8;dl++) Gs[0][dl][tid] = gv[dl];
  }
  __syncthreads();

  int t0 = wid*2, t1 = wid*2+1;
  int lane15 = lane&15, lgrp = lane>>4;
  int rowA0 = lane15, rowA1 = 16 + lane15;
  int swzA = (rowA0 & 7) << 4;                    // rowA1&7 == rowA0&7
  f32x4 acc00={0,0,0,0}, acc01={0,0,0,0}, acc10={0,0,0,0}, acc11={0,0,0,0};
  const char* XsB = (const char*)Xs;

  for (int c=0; c<8; ++c) {
    int cur = c & 1;
    // issue next chunk's global load early (hides under agg)
    half8 gv;
    if (c < 7) {
      int j = Js[tid];
      gv = *(const half8*)(nfeatT + ((size_t)bb*MM + j)*64 + (c+1)*8);
    }
    // agg: wave's 4 pts, 8 d each, lane = w channel (fdot2, broadcast LDS reads)
    #pragma unroll
    for (int pti=0; pti<4; ++pti) {
      int ptl = wid*4 + pti;
      int ptk0 = ptl*16;
      int swz = (ptl&7)<<4;
      #pragma unroll
      for (int dl=0; dl<8; ++dl) {
        float a = 0.f;
        #pragma unroll
        for (int k2=0;k2<8;k2++) {
          half2t g = *(const half2t*)&Gs[cur][dl][ptk0 + 2*k2];
          a = fdot2f(g, wm2[pti][k2], a);
        }
        int off = ptl*1024 + ((dl*64 + lane)<<1);
        *(_Float16*)((char*)Xs + (off ^ swz)) = (_Float16)a;
      }
    }
    // write staged data into other Gs buffer (waits vmcnt)
    if (c < 7) {
      #pragma unroll
      for (int dl=0;dl<8;dl++) Gs[cur^1][dl][tid] = gv[dl];
    }
    __syncthreads();          // Xs + Gs[next] visible
    // mfma over this chunk's 16 k-steps
    #pragma unroll
    for (int s=0; s<16; ++s) {
      int kb = (s*32 + lgrp*8)*2;
      half8 A0 = *(const half8*)(XsB + ((rowA0*1024 + kb) ^ swzA));
      half8 A1 = *(const half8*)(XsB + ((rowA1*1024 + kb) ^ swzA));
      int sg = c*16 + s;
      half8 B0 = *(const half8*)(wfB + ((size_t)(sg*16 + t0)*64 + lane)*8);
      half8 B1 = *(const half8*)(wfB + ((size_t)(sg*16 + t1)*64 + lane)*8);
      acc00 = __builtin_amdgcn_mfma_f32_16x16x32_f16(A0,B0,acc00,0,0,0);
      acc01 = __builtin_amdgcn_mfma_f32_16x16x32_f16(A0,B1,acc01,0,0,0);
      acc10 = __builtin_amdgcn_mfma_f32_16x16x32_f16(A1,B0,acc10,0,0,0);
      acc11 = __builtin_amdgcn_mfma_f32_16x16x32_f16(A1,B1,acc11,0,0,0);
    }
    __syncthreads();          // Xs consumed before next agg overwrites
  }
  { // feature tail: copy featT rows into Xs (128 k)
    int ptl = tid>>4, c8 = (tid&15)*8;
    size_t p = (size_t)blk*32 + ptl;
    half8 v = *(const half8*)(featT + p*128 + c8);
    int swz = (ptl&7)<<4;
    *(half8*)((char*)Xs + ((ptl*1024 + c8*2) ^ swz)) = v;
  }
  __syncthreads();
  #pragma unroll
  for (int s=0; s<4; ++s) {
    int kb = (s*32 + lgrp*8)*2;
    half8 A0 = *(const half8*)(XsB + ((rowA0*1024 + kb) ^ swzA));
    half8 A1 = *(const half8*)(XsB + ((rowA1*1024 + kb) ^ swzA));
    int sg = 128 + s;
    half8 B0 = *(const half8*)(wfB + ((size_t)(sg*16 + t0)*64 + lane)*8);
    half8 B1 = *(const half8*)(wfB + ((size_t)(sg*16 + t1)*64 + lane)*8);
    acc00 = __builtin_amdgcn_mfma_f32_16x16x32_f16(A0,B0,acc00,0,0,0);
    acc01 = __builtin_amdgcn_mfma_f32_16x16x32_f16(A0,B1,acc01,0,0,0);
    acc10 = __builtin_amdgcn_mfma_f32_16x16x32_f16(A1,B0,acc10,0,0,0);
    acc11 = __builtin_amdgcn_mfma_f32_16x16x32_f16(A1,B1,acc11,0,0,0);
  }
  // epilogue: C/D layout col=lane&15, row=(lane>>4)*4+j  [m89]
  #pragma unroll
  for (int j=0;j<4;j++) {
    size_t r0 = (size_t)blk*32 + lgrp*4 + j;
    size_t r1 = r0 + 16;
    y16[r0*256 + t0*16 + lane15] = (_Float16)acc00[j];
    y16[r0*256 + t1*16 + lane15] = (_Float16)acc01[j];
    y16[r1*256 + t0*16 + lane15] = (_Float16)acc10[j];
    y16[r1*256 + t1*16 + lane15] = (_Float16)acc11[j];
  }
}

// ---------------------------------------------------------------------------
// Coalesced final-BN stats: 256 blocks x 128 rows; half8 row segments.
__global__ __launch_bounds__(256) void statsf_kernel(const _Float16* __restrict__ y,
                                                     float* __restrict__ stats) {
  __shared__ float s_[8][256], q_[8][256];
  int tid = threadIdx.x;
  int g = tid & 31;            // 16-B column segment
  int rg = tid >> 5;           // row group 0..7
  int o = g*8;
  float sum[8], sq[8];
  #pragma unroll
  for (int j=0;j<8;j++){ sum[j]=0.f; sq[j]=0.f; }
  size_t base = (size_t)blockIdx.x * 128;
  for (int r=rg; r<128; r+=8) {
    half8 v = *(const half8*)(y + (base + r)*256 + o);
    #pragma unroll
    for (int j=0;j<8;j++){ float f=(float)v[j]; sum[j]+=f; sq[j]+=f*f; }
  }
  #pragma unroll
  for (int j=0;j<8;j++){ s_[rg][o+j]=sum[j]; q_[rg][o+j]=sq[j]; }
  __syncthreads();
  float ts=0.f, tq=0.f;
  #pragma unroll
  for (int j=0;j<8;j++){ ts += s_[j][tid]; tq += q_[j][tid]; }
  atomicAdd(&stats[SUMF+tid], ts);
  atomicAdd(&stats[SQF+tid], tq);
}

__global__ __launch_bounds__(256) void final_kernel(const _Float16* __restrict__ y,
    const float* __restrict__ stats, float* __restrict__ out) {
  __shared__ float t[64][65];
  int o0 = blockIdx.x*64, n0 = blockIdx.y*64, b = blockIdx.z;
  int tid=threadIdx.x, c=tid&63, r4=tid>>6;
  #pragma unroll
  for (int i=0;i<16;i++) {
    int r = i*4 + r4;
    t[r][c] = (float)y[((size_t)b*NN + n0 + r)*256 + o0 + c];
  }
  __syncthreads();
  #pragma unroll
  for (int i=0;i<16;i++) {
    int orow = i*4 + r4;
    float sc = stats[SCF + o0 + orow], sh = stats[SHF + o0 + orow];
    out[((size_t)b*OCC + o0 + orow)*NN + n0 + c] = fmaxf(t[c][orow]*sc + sh, 0.f);
  }
}

// ---------------------------------------------------------------------------
extern "C" void kernel_launch(void* const* d_in, const int* in_sizes, int n_in,
                              void* d_out, int out_size, void* d_ws, size_t ws_size,
                              hipStream_t stream) {
  const float* xyz   = (const float*)d_in[0];
  const float* nxyz  = (const float*)d_in[1];
  const float* feat  = (const float*)d_in[2];
  const float* nfeat = (const float*)d_in[3];
  const float* w1    = (const float*)d_in[4];
  const float* w2    = (const float*)d_in[5];
  const float* w3    = (const float*)d_in[6];
  const float* g1    = (const float*)d_in[7];
  const float* b1    = (const float*)d_in[8];
  const float* g2    = (const float*)d_in[9];
  const float* b2    = (const float*)d_in[10];
  const float* g3    = (const float*)d_in[11];
  const float* b3    = (const float*)d_in[12];
  const float* wf    = (const float*)d_in[13];
  const float* gf    = (const float*)d_in[14];
  const float* bf    = (const float*)d_in[15];

  char* ws = (char*)d_ws;
  int*      idx    = (int*)(ws + IDX_OFF);
  float*    stats  = (float*)(ws + ST_OFF);
  _Float16* wfB    = (_Float16*)(ws + WFB_OFF);
  _Float16* nfT    = (_Float16*)(ws + NFT_OFF);
  _Float16* fT     = (_Float16*)(ws + FTT_OFF);
  _Float16* y16    = (_Float16*)(ws + Y16_OFF);
  _Float16* s23    = (_Float16*)(ws + S23_OFF);
  float2*   cand   = (float2*)(ws + CAND_OFF);
  float*    outp   = (float*)d_out;

  hipMemsetAsync(stats, 0, 8192, stream);

  // independent prep
  nfeatT_kernel<<<dim3(MM/64, BB), 256, 0, stream>>>(nfeat, nfT);
  featT_kernel<<<dim3(NN/64, DD/64, BB), 256, 0, stream>>>(feat, fT);
  wfb_kernel<<<dim3(KTOT/32, OCC/16), 256, 0, stream>>>(wf, wfB);

  // knn + bn1
  knn_part8<<<dim3(NN/256, NSPLIT, BB), 256, 0, stream>>>(xyz, nxyz, cand);
  knn_merge<<<NPTS/256, 256, 0, stream>>>(xyz, nxyz, cand, idx, stats);
  bn1_kernel<<<1, 64, 0, stream>>>(w1, g1, b1, stats);

  // weightnet chain with materialized s2/s3
  k2_kernel<<<NPTS/32, 256, 0, stream>>>(xyz, nxyz, idx, w1, w2, stats, s23, stats);
  bnsmall_kernel<<<1, 64, 0, stream>>>(g2, b2, stats, SUM2, SQ2, SC2, SH2, 1.0f/(float)CNT1);
  k3_kernel<<<NPTS/32, 256, 0, stream>>>(w3, stats, s23, stats);
  bnsmall_kernel<<<1, 64, 0, stream>>>(g3, b3, stats, SUM3, SQ3, SC3, SH3, 1.0f/(float)CNT1);

  // fused agg + final GEMM (MFMA f16)
  fused2_kernel<<<NPTS/32, 512, 0, stream>>>(nfT, fT, idx, s23, stats, wfB, y16);

  // final BN + transpose
  statsf_kernel<<<NPTS/128, 256, 0, stream>>>(y16, stats);
  bnsmall_kernel<<<1, 256, 0, stream>>>(gf, bf, stats, SUMF, SQF, SCF, SHF, 1.0f/(float)NPTS);
  final_kernel<<<dim3(OCC/64, NN/64, BB), 256, 0, stream>>>(y16, stats, outp);
}

// Round 6
// 790.268 us; speedup vs baseline: 6.2192x; 1.2675x over previous
//
#include <hip/hip_runtime.h>

// Problem constants
#define BB   4
#define NN   8192
#define MM   2048
#define KNNK 16
#define DD   128
#define DPC  64
#define WCC  64
#define OCC  256
#define KTOT 4224          // DPC*WCC + DD
#define EPSV 1e-5f
#define NPTS (BB*NN)       // 32768
#define CNT1 (NPTS*KNNK)   // 524288
#define NSPLIT 8
#define MCAND (MM/NSPLIT)  // 256 candidates per split
#define MCHUNK 16384       // GEMM/agg M-chunk (2 chunks)

// stats region float indices
enum { REL0=0, SC1=16, SH1=80, SUM2=144, SQ2=208, SC2=272, SH2=336,
       SUM3=400, SQ3=464, SC3=528, SH3=592, SUMF=656, SQF=912, SCF=1168, SHF=1424 };

// workspace byte offsets (total ~227.6 MB)
#define IDX_OFF   0u           // 32768*16*4 = 2097152
#define ST_OFF    2097152u     // 8192
#define WFB_OFF   2105344u     // 132*16*64*8*2 = 2162688
#define NFT_OFF   4268032u     // 4*2048*64*2 = 1048576
#define Y16_OFF   5316608u     // 32768*256*2 = 16777216
#define S23_OFF   22093824u    // 524288*64*2 = 67108864
#define CAND_OFF  S23_OFF      // cand (33.5 MB) aliases s23: dead before k2 runs
#define XG_OFF    89202688u    // 16384*4224*2 = 138412032

typedef _Float16 half8 __attribute__((ext_vector_type(8)));
typedef _Float16 half2t __attribute__((ext_vector_type(2)));
typedef float    f32x4 __attribute__((ext_vector_type(4)));

#if __has_builtin(__builtin_amdgcn_fdot2)
__device__ __forceinline__ float fdot2f(half2t a, half2t b, float c) {
  return __builtin_amdgcn_fdot2(a, b, c, false);
}
#else
__device__ __forceinline__ float fdot2f(half2t a, half2t b, float c) {
  return c + (float)a[0]*(float)b[0] + (float)a[1]*(float)b[1];
}
#endif

#if __has_builtin(__builtin_amdgcn_global_load_lds)
#define HAS_GLDS 1
#endif

// async global->LDS, 16B per lane. dest semantics: wave-uniform base + lane*16.
__device__ __forceinline__ void gload16(const void* g, void* l) {
#ifdef HAS_GLDS
  __builtin_amdgcn_global_load_lds((const __attribute__((address_space(1))) void*)g,
                                   (__attribute__((address_space(3))) void*)l, 16, 0, 0);
#else
  int lane = threadIdx.x & 63;
  *(half8*)((char*)l + lane*16) = *(const half8*)g;
#endif
}

// ---------------------------------------------------------------------------
// KNN over one split (256 candidates).
__global__ __launch_bounds__(256) void knn_part8(
    const float* __restrict__ xyz, const float* __restrict__ nxyz,
    float2* __restrict__ cand) {
  __shared__ float4 sc4[MCAND];
  int b = blockIdx.z, h = blockIdx.y;
  int mbase = h * MCAND;
  const float* np_ = nxyz + ((size_t)b*MM + mbase)*3;
  if (threadIdx.x < MCAND) {
    int i = threadIdx.x;
    float x = np_[i*3+0], y = np_[i*3+1], z = np_[i*3+2];
    sc4[i] = make_float4(x, y, z, x*x+y*y+z*z);
  }
  __syncthreads();
  int n = blockIdx.x*256 + threadIdx.x;
  const float* pp = xyz + ((size_t)b*NN + n)*3;
  float px=pp[0], py=pp[1], pz=pp[2];
  float pn = px*px + py*py + pz*pz;
  float dist[KNNK]; int ind[KNNK];
  #pragma unroll
  for (int k=0;k<KNNK;k++){ dist[k]=3.0e38f; ind[k]=0; }
  #pragma unroll 2
  for (int m=0;m<MCAND;m++) {
    float4 c = sc4[m];
    float t = fmaf(px, c.x, fmaf(py, c.y, pz*c.z));
    float d = fmaf(-2.0f, t, pn + c.w);
    if (__any(d < dist[KNNK-1])) {   // strict <: equal keeps earlier index
      float cd = d; int ci = mbase + m;
      #pragma unroll
      for (int j=0;j<KNNK;j++) {
        bool ins = cd < dist[j];
        float nd = ins ? cd : dist[j];
        int   ni = ins ? ci : ind[j];
        cd = ins ? dist[j] : cd;
        ci = ins ? ind[j]  : ci;
        dist[j] = nd; ind[j] = ni;
      }
    }
  }
  float2* op = cand + (((size_t)b*NN + n)*NSPLIT + h)*16;
  #pragma unroll
  for (int k=0;k<KNNK;k++) op[k] = make_float2(dist[k], __int_as_float(ind[k]));
}

// Merge NSPLIT sorted 16-lists -> final idx; accumulate rel moments.
__global__ __launch_bounds__(256) void knn_merge(
    const float* __restrict__ xyz, const float* __restrict__ nxyz,
    const float2* __restrict__ cand, int* __restrict__ idxo,
    float* __restrict__ stats) {
  __shared__ float sred[9];
  if (threadIdx.x < 9) sred[threadIdx.x] = 0.f;
  __syncthreads();
  int p = blockIdx.x*256 + threadIdx.x;
  int b = p >> 13;
  const float2* ca = cand + (size_t)p*(NSPLIT*16);
  float dist[16]; int ind[16];
  #pragma unroll
  for (int k=0;k<16;k++) { float2 f = ca[k]; dist[k]=f.x; ind[k]=__float_as_int(f.y); }
  for (int h=1; h<NSPLIT; ++h) {
    #pragma unroll
    for (int k=0;k<16;k++) {
      float2 f = ca[h*16+k];
      float cd = f.x; int ci = __float_as_int(f.y);
      if (__any(cd < dist[15])) {
        #pragma unroll
        for (int j=0;j<16;j++) {
          bool ins = cd < dist[j];
          float nd = ins ? cd : dist[j];
          int   ni = ins ? ci : ind[j];
          cd = ins ? dist[j] : cd;
          ci = ins ? ind[j]  : ci;
          dist[j] = nd; ind[j] = ni;
        }
      }
    }
  }
  const float* pp = xyz + (size_t)p*3;
  float px=pp[0], py=pp[1], pz=pp[2];
  int* op = idxo + (size_t)p*16;
  float s0=0,s1=0,s2=0,s3=0,s4=0,s5=0,s6=0,s7=0,s8=0;
  #pragma unroll
  for (int k=0;k<16;k++) {
    op[k] = ind[k];
    const float* q = nxyz + ((size_t)b*MM + ind[k])*3;
    float rx=q[0]-px, ry=q[1]-py, rz=q[2]-pz;
    s0+=rx; s1+=ry; s2+=rz;
    s3+=rx*rx; s4+=rx*ry; s5+=rx*rz; s6+=ry*ry; s7+=ry*rz; s8+=rz*rz;
  }
  atomicAdd(&sred[0],s0); atomicAdd(&sred[1],s1); atomicAdd(&sred[2],s2);
  atomicAdd(&sred[3],s3); atomicAdd(&sred[4],s4); atomicAdd(&sred[5],s5);
  atomicAdd(&sred[6],s6); atomicAdd(&sred[7],s7); atomicAdd(&sred[8],s8);
  __syncthreads();
  if (threadIdx.x < 9) atomicAdd(&stats[REL0 + threadIdx.x], sred[threadIdx.x]);
}

// ---------------------------------------------------------------------------
__global__ void bn1_kernel(const float* __restrict__ w1, const float* __restrict__ g1,
                           const float* __restrict__ b1, float* __restrict__ stats) {
  int d = threadIdx.x;
  float inv = 1.0f / (float)CNT1;
  float mx=stats[0]*inv, my=stats[1]*inv, mz=stats[2]*inv;
  float xx=stats[3]*inv, xy=stats[4]*inv, xz=stats[5]*inv,
        yy=stats[6]*inv, yz=stats[7]*inv, zz=stats[8]*inv;
  float wx=w1[0*WCC+d], wy=w1[1*WCC+d], wz=w1[2*WCC+d];
  float m  = mx*wx + my*wy + mz*wz;
  float e2 = wx*wx*xx + wy*wy*yy + wz*wz*zz + 2.0f*(wx*wy*xy + wx*wz*xz + wy*wz*yz);
  float v  = e2 - m*m;
  float sc = rsqrtf(v + EPSV) * g1[d];
  stats[SC1+d] = sc;
  stats[SH1+d] = b1[d] - m*sc;
}

__global__ void bnsmall_kernel(const float* __restrict__ g, const float* __restrict__ b,
                               float* __restrict__ stats, int sumOff, int sqOff,
                               int scOff, int shOff, float inv) {
  int d = threadIdx.x;
  float m = stats[sumOff+d]*inv;
  float v = stats[sqOff+d]*inv - m*m;
  float sc = rsqrtf(v + EPSV) * g[d];
  stats[scOff+d] = sc;
  stats[shOff+d] = b[d] - m*sc;
}

// ---------------------------------------------------------------------------
// K2: rel -> h1 -> s2; BN2 stats; store s2 (f16). 32 pts/block, 8/wave, lane=w.
__global__ __launch_bounds__(256, 4) void k2_kernel(
    const float* __restrict__ xyz, const float* __restrict__ nxyz,
    const int* __restrict__ idx, const float* __restrict__ w1,
    const float* __restrict__ w2, const float* __restrict__ stats,
    _Float16* __restrict__ s23, float* __restrict__ statw) {
  __shared__ __align__(16) float hb[4][KNNK*WCC];
  __shared__ float red[4][128];
  int tid=threadIdx.x, lane=tid&63, wid=tid>>6;
  float w2col[64];
  #pragma unroll
  for (int c=0;c<64;c++) w2col[c] = w2[c*64+lane];
  float w1x=w1[lane], w1y=w1[64+lane], w1z=w1[128+lane];
  float sc1=stats[SC1+lane], sh1=stats[SH1+lane];
  float* hbw = hb[wid];
  float sum=0.f, sq=0.f;
  int pbase = blockIdx.x*32 + wid*8;
  for (int pt=0; pt<8; ++pt) {
    int p = pbase + pt;
    int b = p >> 13;
    const float* pp = xyz + (size_t)p*3;
    float px=pp[0], py=pp[1], pz=pp[2];
    const int* ip = idx + (size_t)p*16;
    #pragma unroll
    for (int k=0;k<16;k++) {
      int j = ip[k];
      const float* q = nxyz + ((size_t)b*MM + j)*3;
      float s1v = (q[0]-px)*w1x + (q[1]-py)*w1y + (q[2]-pz)*w1z;
      hbw[k*64+lane] = fmaxf(s1v*sc1 + sh1, 0.f);
    }
    for (int k=0;k<16;k++) {
      float acc = 0.f;
      #pragma unroll
      for (int c=0;c<64;c+=4) {
        float4 h = *(const float4*)&hbw[k*64+c];
        acc = fmaf(h.x, w2col[c+0], acc);
        acc = fmaf(h.y, w2col[c+1], acc);
        acc = fmaf(h.z, w2col[c+2], acc);
        acc = fmaf(h.w, w2col[c+3], acc);
      }
      sum += acc; sq += acc*acc;
      s23[((size_t)p*16 + k)*64 + lane] = (_Float16)acc;
    }
  }
  red[wid][lane]=sum; red[wid][64+lane]=sq;
  __syncthreads();
  if (tid < 128) {
    float v = red[0][tid]+red[1][tid]+red[2][tid]+red[3][tid];
    atomicAdd(&statw[SUM2+tid], v);
  }
}

// K3: s2 -> h2 -> s3 (in place); BN3 stats.
__global__ __launch_bounds__(256, 4) void k3_kernel(
    const float* __restrict__ w3, const float* __restrict__ stats,
    _Float16* __restrict__ s23, float* __restrict__ statw) {
  __shared__ __align__(16) float hb[4][KNNK*WCC];
  __shared__ float red[4][128];
  int tid=threadIdx.x, lane=tid&63, wid=tid>>6;
  float w3col[64];
  #pragma unroll
  for (int c=0;c<64;c++) w3col[c] = w3[c*64+lane];
  float sc2=stats[SC2+lane], sh2=stats[SH2+lane];
  float* hbw = hb[wid];
  float sum=0.f, sq=0.f;
  int pbase = blockIdx.x*32 + wid*8;
  for (int pt=0; pt<8; ++pt) {
    size_t p = pbase + pt;
    #pragma unroll
    for (int k=0;k<16;k++) {
      float v = (float)s23[(p*16 + k)*64 + lane];
      hbw[k*64+lane] = fmaxf(v*sc2 + sh2, 0.f);
    }
    for (int k=0;k<16;k++) {
      float acc = 0.f;
      #pragma unroll
      for (int c=0;c<64;c+=4) {
        float4 h = *(const float4*)&hbw[k*64+c];
        acc = fmaf(h.x, w3col[c+0], acc);
        acc = fmaf(h.y, w3col[c+1], acc);
        acc = fmaf(h.z, w3col[c+2], acc);
        acc = fmaf(h.w, w3col[c+3], acc);
      }
      sum += acc; sq += acc*acc;
      s23[(p*16 + k)*64 + lane] = (_Float16)acc;
    }
  }
  red[wid][lane]=sum; red[wid][64+lane]=sq;
  __syncthreads();
  if (tid < 128) {
    float v = red[0][tid]+red[1][tid]+red[2][tid]+red[3][tid];
    atomicAdd(&statw[SUM3+tid], v);
  }
}

// ---------------------------------------------------------------------------
// nfeat (B,DP,M) f32 -> nfeatT (B,M,DP) f16
__global__ __launch_bounds__(256) void nfeatT_kernel(const float* __restrict__ nf,
                                                     _Float16* __restrict__ nfT) {
  __shared__ float t[64][65];
  int m0 = blockIdx.x*64, b = blockIdx.y;
  int tid=threadIdx.x, c=tid&63, r4=tid>>6;
  #pragma unroll
  for (int i=0;i<16;i++) {
    int d = i*4 + r4;
    t[d][c] = nf[((size_t)b*DPC + d)*MM + m0 + c];
  }
  __syncthreads();
  #pragma unroll
  for (int i=0;i<16;i++) {
    int m = i*4 + r4;
    nfT[((size_t)b*MM + m0 + m)*64 + c] = (_Float16)t[c][m];
  }
}

// feature tail: feat (B,D,N) f32 -> Xg cols 4096..4223 (per chunk, 2 batches)
__global__ __launch_bounds__(256) void ftail_kernel(const float* __restrict__ f,
    _Float16* __restrict__ Xg, int b0) {
  __shared__ float t[64][65];
  int n0 = blockIdx.x*64, c0 = blockIdx.y*64, bz = blockIdx.z;
  int b = b0 + bz;
  int tid=threadIdx.x, c=tid&63, r4=tid>>6;
  #pragma unroll
  for (int i=0;i<16;i++) {
    int d = i*4 + r4;
    t[d][c] = f[((size_t)b*DD + c0 + d)*NN + n0 + c];
  }
  __syncthreads();
  #pragma unroll
  for (int i=0;i<16;i++) {
    int n = i*4 + r4;
    Xg[((size_t)bz*NN + n0 + n)*KTOT + 4096 + c0 + c] = (_Float16)t[c][n];
  }
}

// wf (KTOT x OCC f32) -> wfB: B-fragment order. Fragment (s,t): lane l holds
// k = s*32 + (l>>4)*8 + i,  oc = t*16 + (l&15)  (same lane->k map as A-frags).
__global__ __launch_bounds__(256) void wfb_kernel(const float* __restrict__ wf,
                                                  _Float16* __restrict__ wfB) {
  int s = blockIdx.x, t = blockIdx.y;
  int tid = threadIdx.x;
  int l = tid >> 2, i2 = (tid & 3)*2;
  int k  = s*32 + (l>>4)*8 + i2;
  int oc = t*16 + (l&15);
  float a = wf[(size_t)k*OCC + oc];
  float b = wf[(size_t)(k+1)*OCC + oc];
  half2t h = { (_Float16)a, (_Float16)b };
  *(half2t*)(wfB + (((size_t)s*16 + t)*64 + l)*8 + i2) = h;
}

// ---------------------------------------------------------------------------
// agg3: X[p][d*64+w] = sum_k G[k][d]*wm[k][w], written to Xg (row stride 4224).
// 32 pts/block, 512 thr. Gs double-buffered [dl][ptk]; b128 broadcast reads.
__global__ __launch_bounds__(512) void agg3_kernel(
    const _Float16* __restrict__ nfT, const int* __restrict__ idx,
    const _Float16* __restrict__ s23, const float* __restrict__ stats,
    _Float16* __restrict__ Xg, int pbase) {
  __shared__ __align__(16) _Float16 Gs[2][8][512];
  int tid=threadIdx.x, lane=tid&63, wid=tid>>6;
  int blk = blockIdx.x;
  int p0 = pbase + blk*32;
  int bb = p0 >> 13;
  int jreg = idx[(size_t)p0*16 + tid];       // ptk = tid
  const _Float16* gsrc = nfT + ((size_t)bb*MM + jreg)*64;
  half8 gv = *(const half8*)gsrc;            // chunk 0
  float sc3 = stats[SC3+lane], sh3 = stats[SH3+lane];
  half2t wm2[4][8];
  #pragma unroll
  for (int pti=0; pti<4; ++pti) {
    size_t p = (size_t)p0 + wid*4 + pti;
    #pragma unroll
    for (int k2=0;k2<8;k2++) {
      float va = fmaxf((float)s23[(p*16 + 2*k2  )*64 + lane]*sc3 + sh3, 0.f);
      float vb = fmaxf((float)s23[(p*16 + 2*k2+1)*64 + lane]*sc3 + sh3, 0.f);
      wm2[pti][k2] = half2t{ (_Float16)va, (_Float16)vb };
    }
  }
  #pragma unroll
  for (int dl=0;dl<8;dl++) Gs[0][dl][tid] = gv[dl];
  __syncthreads();
  size_t xrow0 = (size_t)blk*32;
  for (int c=0; c<8; ++c) {
    int cur = c&1;
    if (c<7) gv = *(const half8*)(gsrc + (c+1)*8);   // prefetch next chunk
    #pragma unroll
    for (int pti=0; pti<4; ++pti) {
      int ptl = wid*4 + pti;
      #pragma unroll
      for (int dl=0; dl<8; ++dl) {
        const _Float16* gp = &Gs[cur][dl][ptl*16];
        half8 ga = *(const half8*)gp;
        half8 gb = *(const half8*)(gp+8);
        float a = 0.f;
        a = fdot2f(__builtin_shufflevector(ga,ga,0,1), wm2[pti][0], a);
        a = fdot2f(__builtin_shufflevector(ga,ga,2,3), wm2[pti][1], a);
        a = fdot2f(__builtin_shufflevector(ga,ga,4,5), wm2[pti][2], a);
        a = fdot2f(__builtin_shufflevector(ga,ga,6,7), wm2[pti][3], a);
        a = fdot2f(__builtin_shufflevector(gb,gb,0,1), wm2[pti][4], a);
        a = fdot2f(__builtin_shufflevector(gb,gb,2,3), wm2[pti][5], a);
        a = fdot2f(__builtin_shufflevector(gb,gb,4,5), wm2[pti][6], a);
        a = fdot2f(__builtin_shufflevector(gb,gb,6,7), wm2[pti][7], a);
        Xg[(xrow0 + ptl)*KTOT + c*512 + dl*64 + lane] = (_Float16)a;
      }
    }
    if (c<7) {
      #pragma unroll
      for (int dl=0;dl<8;dl++) Gs[cur^1][dl][tid] = gv[dl];
    }
    __syncthreads();
  }
}

// ---------------------------------------------------------------------------
// gemmx: y16[chunk rows][256] = Xg (Mx4224 f16) @ wfB (fragment-packed).
// 128x128 tile, 4 waves (2x2), BK=64 double-buffered, global_load_lds staging.
__global__ __launch_bounds__(256, 2) void gemmx_kernel(
    const _Float16* __restrict__ Xg, const _Float16* __restrict__ wfB,
    _Float16* __restrict__ y16, int pbase) {
  __shared__ __align__(16) _Float16 As[2][8192];   // [128 rows][64 k], XOR-swizzled
  __shared__ __align__(16) _Float16 Bs[2][8192];   // [2 sg2][8 t][64 lane][8]
  int tid=threadIdx.x, lane=tid&63, wid=tid>>6;
  int lin = blockIdx.y*2 + blockIdx.x;
  int sw = (lin&7)*32 + (lin>>3);                  // XCD swizzle (256%8==0)
  int mt = sw>>1, nt = sw&1;
  size_t row0 = (size_t)mt*128;
  int wm_ = wid>>1, wn_ = wid&1;
  int r16 = wid*4;
  int arow = lane>>3;                              // row within 8-row region
  int kel = ((lane&7) ^ (arow&7)) << 3;            // pre-swizzled source k (halves)
  f32x4 acc[4][4] = {};

  auto STAGE = [&](int bufi, int s64) {
    #pragma unroll
    for (int i=0;i<4;i++) {
      int reg = r16 + i;
      int grow = reg*8 + arow;
      gload16(Xg + (row0 + grow)*KTOT + (size_t)s64*64 + kel, &As[bufi][reg*512]);
      gload16(wfB + (((size_t)(s64*2 + (reg>>3))*16 + nt*8 + (reg&7))*64 + lane)*8,
              &Bs[bufi][reg*512]);
    }
  };
  auto COMPUTE = [&](int bufi) {
    #pragma unroll
    for (int sg2=0; sg2<2; ++sg2) {
      half8 af[4], bfr[4];
      #pragma unroll
      for (int f=0; f<4; ++f) {
        int row = wm_*64 + f*16 + (lane&15);
        int kb = sg2*64 + ((lane>>4)<<4);
        int off = row*128 + (kb ^ ((row&7)<<4));
        af[f] = *(const half8*)((const char*)&As[bufi][0] + off);
        bfr[f] = *(const half8*)&Bs[bufi][(size_t)(sg2*8 + wn_*4 + f)*512 + lane*8];
      }
      #pragma unroll
      for (int fa=0; fa<4; ++fa)
        #pragma unroll
        for (int fb=0; fb<4; ++fb)
          acc[fa][fb] = __builtin_amdgcn_mfma_f32_16x16x32_f16(af[fa], bfr[fb], acc[fa][fb], 0,0,0);
    }
  };

  STAGE(0, 0);
  int buf = 0;
  for (int s=0; s<66; ++s) {
    if (s < 65) STAGE(buf^1, s+1);
    __syncthreads();
    COMPUTE(buf);
    __syncthreads();
    buf ^= 1;
  }
  // epilogue: C/D layout col=lane&15, row=(lane>>4)*4+j  [m89]
  size_t prow = (size_t)pbase + row0 + wm_*64;
  int oc0 = nt*128 + wn_*64;
  int l15 = lane&15, lg = lane>>4;
  #pragma unroll
  for (int fa=0; fa<4; ++fa)
    #pragma unroll
    for (int j=0;j<4;j++)
      #pragma unroll
      for (int fb=0; fb<4; ++fb)
        y16[(prow + fa*16 + lg*4 + j)*256 + oc0 + fb*16 + l15] = (_Float16)acc[fa][fb][j];
}

// ---------------------------------------------------------------------------
// Coalesced final-BN stats: 256 blocks x 128 rows; half8 row segments.
__global__ __launch_bounds__(256) void statsf_kernel(const _Float16* __restrict__ y,
                                                     float* __restrict__ stats) {
  __shared__ float s_[8][256], q_[8][256];
  int tid = threadIdx.x;
  int g = tid & 31;
  int rg = tid >> 5;
  int o = g*8;
  float sum[8], sq[8];
  #pragma unroll
  for (int j=0;j<8;j++){ sum[j]=0.f; sq[j]=0.f; }
  size_t base = (size_t)blockIdx.x * 128;
  for (int r=rg; r<128; r+=8) {
    half8 v = *(const half8*)(y + (base + r)*256 + o);
    #pragma unroll
    for (int j=0;j<8;j++){ float f=(float)v[j]; sum[j]+=f; sq[j]+=f*f; }
  }
  #pragma unroll
  for (int j=0;j<8;j++){ s_[rg][o+j]=sum[j]; q_[rg][o+j]=sq[j]; }
  __syncthreads();
  float ts=0.f, tq=0.f;
  #pragma unroll
  for (int j=0;j<8;j++){ ts += s_[j][tid]; tq += q_[j][tid]; }
  atomicAdd(&stats[SUMF+tid], ts);
  atomicAdd(&stats[SQF+tid], tq);
}

__global__ __launch_bounds__(256) void final_kernel(const _Float16* __restrict__ y,
    const float* __restrict__ stats, float* __restrict__ out) {
  __shared__ float t[64][65];
  int o0 = blockIdx.x*64, n0 = blockIdx.y*64, b = blockIdx.z;
  int tid=threadIdx.x, c=tid&63, r4=tid>>6;
  #pragma unroll
  for (int i=0;i<16;i++) {
    int r = i*4 + r4;
    t[r][c] = (float)y[((size_t)b*NN + n0 + r)*256 + o0 + c];
  }
  __syncthreads();
  #pragma unroll
  for (int i=0;i<16;i++) {
    int orow = i*4 + r4;
    float sc = stats[SCF + o0 + orow], sh = stats[SHF + o0 + orow];
    out[((size_t)b*OCC + o0 + orow)*NN + n0 + c] = fmaxf(t[c][orow]*sc + sh, 0.f);
  }
}

// ---------------------------------------------------------------------------
extern "C" void kernel_launch(void* const* d_in, const int* in_sizes, int n_in,
                              void* d_out, int out_size, void* d_ws, size_t ws_size,
                              hipStream_t stream) {
  const float* xyz   = (const float*)d_in[0];
  const float* nxyz  = (const float*)d_in[1];
  const float* feat  = (const float*)d_in[2];
  const float* nfeat = (const float*)d_in[3];
  const float* w1    = (const float*)d_in[4];
  const float* w2    = (const float*)d_in[5];
  const float* w3    = (const float*)d_in[6];
  const float* g1    = (const float*)d_in[7];
  const float* b1    = (const float*)d_in[8];
  const float* g2    = (const float*)d_in[9];
  const float* b2    = (const float*)d_in[10];
  const float* g3    = (const float*)d_in[11];
  const float* b3    = (const float*)d_in[12];
  const float* wf    = (const float*)d_in[13];
  const float* gf    = (const float*)d_in[14];
  const float* bf    = (const float*)d_in[15];

  char* ws = (char*)d_ws;
  int*      idx    = (int*)(ws + IDX_OFF);
  float*    stats  = (float*)(ws + ST_OFF);
  _Float16* wfB    = (_Float16*)(ws + WFB_OFF);
  _Float16* nfT    = (_Float16*)(ws + NFT_OFF);
  _Float16* y16    = (_Float16*)(ws + Y16_OFF);
  _Float16* s23    = (_Float16*)(ws + S23_OFF);
  float2*   cand   = (float2*)(ws + CAND_OFF);
  _Float16* Xg     = (_Float16*)(ws + XG_OFF);
  float*    outp   = (float*)d_out;

  hipMemsetAsync(stats, 0, 8192, stream);

  // independent prep
  nfeatT_kernel<<<dim3(MM/64, BB), 256, 0, stream>>>(nfeat, nfT);
  wfb_kernel<<<dim3(KTOT/32, OCC/16), 256, 0, stream>>>(wf, wfB);

  // knn + bn1
  knn_part8<<<dim3(NN/256, NSPLIT, BB), 256, 0, stream>>>(xyz, nxyz, cand);
  knn_merge<<<NPTS/256, 256, 0, stream>>>(xyz, nxyz, cand, idx, stats);
  bn1_kernel<<<1, 64, 0, stream>>>(w1, g1, b1, stats);

  // weightnet chain with materialized s2/s3
  k2_kernel<<<NPTS/32, 256, 0, stream>>>(xyz, nxyz, idx, w1, w2, stats, s23, stats);
  bnsmall_kernel<<<1, 64, 0, stream>>>(g2, b2, stats, SUM2, SQ2, SC2, SH2, 1.0f/(float)CNT1);
  k3_kernel<<<NPTS/32, 256, 0, stream>>>(w3, stats, s23, stats);
  bnsmall_kernel<<<1, 64, 0, stream>>>(g3, b3, stats, SUM3, SQ3, SC3, SH3, 1.0f/(float)CNT1);

  // agg -> X (chunked) -> GEMM
  for (int ch=0; ch<2; ++ch) {
    int pbase = ch*MCHUNK;
    agg3_kernel<<<MCHUNK/32, 512, 0, stream>>>(nfT, idx, s23, stats, Xg, pbase);
    ftail_kernel<<<dim3(NN/64, DD/64, 2), 256, 0, stream>>>(feat, Xg, pbase >> 13);
    gemmx_kernel<<<dim3(2, MCHUNK/128), 256, 0, stream>>>(Xg, wfB, y16, pbase);
  }

  // final BN + transpose
  statsf_kernel<<<NPTS/128, 256, 0, stream>>>(y16, stats);
  bnsmall_kernel<<<1, 256, 0, stream>>>(gf, bf, stats, SUMF, SQF, SCF, SHF, 1.0f/(float)NPTS);
  final_kernel<<<dim3(OCC/64, NN/64, BB), 256, 0, stream>>>(y16, stats, outp);
}